// Round 1
// baseline (1013.764 us; speedup 1.0000x reference)
//
#include <hip/hip_runtime.h>

#define DEVI __device__ __forceinline__

using u16 = unsigned short;
using u32 = unsigned int;
using u64 = unsigned long long;

typedef __bf16 bf16x8 __attribute__((ext_vector_type(8)));
typedef float  f32x4  __attribute__((ext_vector_type(4)));

constexpr int BB = 4, NN = 4096, DD = 1024, HH = 16, DH = 64, MF = 256;
constexpr int RT = BB * NN;                       // 16384 rows total
constexpr float DN    = 0.35355339059327373f;     // 64^-0.25
constexpr float RATIO = 0.0625f;                  // 256^-0.5
constexpr float DIAGC = 0.0625f;                  // 0.5 * DN^2
constexpr float KEPSC = 1e-3f;

// ---------- scalar helpers ----------
DEVI u16 f2bf(float f) {
  u32 u = __float_as_uint(f);
  u32 r = u + 0x7fffu + ((u >> 16) & 1u);   // RNE
  return (u16)(r >> 16);
}
DEVI float bf2f(u16 u) { return __uint_as_float(((u32)u) << 16); }
DEVI u32 fenc(float f) { u32 u = __float_as_uint(f); return (u & 0x80000000u) ? ~u : (u | 0x80000000u); }
DEVI float fdec(u32 m) { u32 u = (m & 0x80000000u) ? (m ^ 0x80000000u) : ~m; return __uint_as_float(u); }

// ---------- global_load_lds (CK addrspace pattern) ----------
typedef void __attribute__((address_space(1)))* gas1;
typedef void __attribute__((address_space(3)))* las3;
DEVI void gload_lds16(const void* g, void* l) {
  __builtin_amdgcn_global_load_lds((gas1)(u64)g, (las3)(u32)(u64)l, 16, 0, 0);
}

// swizzled fragment read from a [128][64]-bf16 LDS tile (row stride 128B)
DEVI bf16x8 ldswz(const u16* base, int row, int kbyte) {
  int p = (row << 7) + kbyte;
  p ^= (row & 7) << 4;                      // same involution as the staging side
  return *(const bf16x8*)((const char*)base + p);
}

// ============================================================
// casts
// ============================================================
__global__ void cast_kernel(const float* __restrict__ in, u16* __restrict__ out, int n4) {
  int i = blockIdx.x * 256 + threadIdx.x;
  int stride = gridDim.x * 256;
  for (; i < n4; i += stride) {
    float4 v = ((const float4*)in)[i];
    ushort4 o; o.x = f2bf(v.x); o.y = f2bf(v.y); o.z = f2bf(v.z); o.w = f2bf(v.w);
    ((ushort4*)out)[i] = o;
  }
}

__global__ void cast_proj_kernel(const float* __restrict__ in, u16* __restrict__ out) {
  int i = blockIdx.x * 256 + threadIdx.x;   // 4096 threads, 16384 elems
  float4 v = ((const float4*)in)[i];
  ushort4 o; o.x = f2bf(v.x * DN); o.y = f2bf(v.y * DN); o.z = f2bf(v.z * DN); o.w = f2bf(v.w * DN);
  ((ushort4*)out)[i] = o;
}

// ============================================================
// GEMM: C[i,j] = sum_k A[i,k] * B[j,k]   (both K-contiguous, bf16)
// 128x128 tile, BK=64, 4 waves (2x2), 16x16x32 MFMA, gload_lds + XOR swizzle
// EPI 0: C->bf16 | 1: +bias+add32 -> f32 | 2: +bias, gelu -> bf16 | 3: +bias -> bf16
// ============================================================
template <int EPI>
__global__ __launch_bounds__(256, 2) void gemm_bt(
    const u16* __restrict__ A, const u16* __restrict__ Bm,
    u16* __restrict__ Cb, float* __restrict__ Cf,
    const float* __restrict__ bias, const float* __restrict__ add32,
    int M, int Ncols, int K)
{
  __shared__ __align__(16) u16 sA[128 * 64];
  __shared__ __align__(16) u16 sB[128 * 64];
  const int tid = threadIdx.x, lane = tid & 63;
  const int wv = tid >> 6, wr = wv >> 1, wc = wv & 1;
  const int bm = blockIdx.y, bn = blockIdx.x;

  f32x4 acc[4][4] = {};

  int rowS[4], colS[4], ldsb[4];
#pragma unroll
  for (int it = 0; it < 4; ++it) {
    int p = (it * 256 + tid) * 16;                // linear LDS byte this lane fills
    ldsb[it] = (it * 256 + (tid & ~63)) * 16;     // wave-uniform base
    int sp = p ^ (((p >> 7) & 7) << 4);           // inverse-swizzled source position
    rowS[it] = sp >> 7;
    colS[it] = (sp >> 1) & 63;
  }
  const size_t baseA = (size_t)bm * 128, baseB = (size_t)bn * 128;

  for (int kt = 0; kt < K; kt += 64) {
#pragma unroll
    for (int it = 0; it < 4; ++it)
      gload_lds16(A + (baseA + rowS[it]) * K + kt + colS[it], (char*)sA + ldsb[it]);
#pragma unroll
    for (int it = 0; it < 4; ++it)
      gload_lds16(Bm + (baseB + rowS[it]) * K + kt + colS[it], (char*)sB + ldsb[it]);
    __syncthreads();
#pragma unroll
    for (int kk = 0; kk < 2; ++kk) {
      const int kbyte = kk * 64 + ((lane >> 4) << 4);
      bf16x8 a[4], b[4];
#pragma unroll
      for (int i = 0; i < 4; ++i) a[i] = ldswz(sA, wr * 64 + i * 16 + (lane & 15), kbyte);
#pragma unroll
      for (int i = 0; i < 4; ++i) b[i] = ldswz(sB, wc * 64 + i * 16 + (lane & 15), kbyte);
#pragma unroll
      for (int i = 0; i < 4; ++i)
#pragma unroll
        for (int j = 0; j < 4; ++j)
          acc[i][j] = __builtin_amdgcn_mfma_f32_16x16x32_bf16(a[i], b[j], acc[i][j], 0, 0, 0);
    }
    __syncthreads();
  }

#pragma unroll
  for (int i = 0; i < 4; ++i) {
    const int gr0 = bm * 128 + wr * 64 + i * 16 + ((lane >> 4) << 2);
#pragma unroll
    for (int j = 0; j < 4; ++j) {
      const int gc = bn * 128 + wc * 64 + j * 16 + (lane & 15);
#pragma unroll
      for (int r = 0; r < 4; ++r) {
        const size_t o = (size_t)(gr0 + r) * Ncols + gc;
        const float v = acc[i][j][r];
        if constexpr (EPI == 0) {
          Cb[o] = f2bf(v);
        } else if constexpr (EPI == 1) {
          Cf[o] = v + bias[gc] + add32[o];
        } else if constexpr (EPI == 2) {
          float t = v + bias[gc];
          Cb[o] = f2bf(0.5f * t * (1.0f + erff(t * 0.70710678118654752f)));
        } else {
          Cb[o] = f2bf(v + bias[gc]);
        }
      }
    }
  }
}

// ============================================================
// key pass 1: global max of data_dash (exact via monotone-uint atomicMax)
// ============================================================
__global__ __launch_bounds__(256) void kmax_kernel(
    const u16* __restrict__ kbuf, const u16* __restrict__ projb, u32* __restrict__ stab)
{
  __shared__ __align__(16) u16 sX[64 * 72];
  const int tid = threadIdx.x, lane = tid & 63, wv = tid >> 6;
  const int bh = blockIdx.x, b = bh >> 4, h = bh & 15;
  const int n0 = blockIdx.y * 64;

  for (int i = tid; i < 512; i += 256) {
    int r = i >> 3, c8 = (i & 7) << 3;
    uint4 v = *(const uint4*)(kbuf + ((size_t)(b * NN + n0 + r)) * DD + h * DH + c8);
    *(uint4*)&sX[r * 72 + c8] = v;
  }
  __syncthreads();

  f32x4 dacc[16] = {};
#pragma unroll
  for (int kk = 0; kk < 2; ++kk) {
    const int ko = kk * 32 + ((lane >> 4) << 3);
    bf16x8 a = *(const bf16x8*)&sX[(wv * 16 + (lane & 15)) * 72 + ko];
#pragma unroll
    for (int f = 0; f < 16; ++f) {
      bf16x8 bb = *(const bf16x8*)(projb + (f * 16 + (lane & 15)) * 64 + ko);
      dacc[f] = __builtin_amdgcn_mfma_f32_16x16x32_bf16(a, bb, dacc[f], 0, 0, 0);
    }
  }
  float mx = -1e30f;
#pragma unroll
  for (int f = 0; f < 16; ++f)
#pragma unroll
    for (int r = 0; r < 4; ++r) mx = fmaxf(mx, dacc[f][r]);
#pragma unroll
  for (int m = 1; m < 64; m <<= 1) mx = fmaxf(mx, __shfl_xor(mx, m));
  if (lane == 0) atomicMax(stab, fenc(mx));
}

// ============================================================
// key pass 2: kp -> k_sum[m], ctxT[j,m] += sum_n v[n,j]*kp[n,m]
// ============================================================
__global__ __launch_bounds__(256, 1) void kctx_kernel(
    const u16* __restrict__ kbuf, const u16* __restrict__ vbuf,
    const u16* __restrict__ projb, const u32* __restrict__ stab_u,
    float* __restrict__ ctxT, float* __restrict__ ksum)
{
  __shared__ __align__(16) u16 sX[64 * 72];
  __shared__ __align__(16) u16 sVT[64 * 72];
  __shared__ __align__(16) u16 sKpT[256 * 72];
  __shared__ float sDiag[64];
  const int tid = threadIdx.x, lane = tid & 63, wv = tid >> 6;
  const int bh = blockIdx.x, b = bh >> 4, h = bh & 15;
  const float stab = fdec(stab_u[0]);

  f32x4 cacc[16] = {};
  float ksacc[16] = {};
  const int row_base = wv * 16 + ((lane >> 4) << 2);

  for (int t = 0; t < 16; ++t) {
    const int n0 = blockIdx.y * 1024 + t * 64;
    if (t) __syncthreads();
    for (int i = tid; i < 512; i += 256) {
      int r = i >> 3, c8 = (i & 7) << 3;
      size_t g = ((size_t)(b * NN + n0 + r)) * DD + h * DH + c8;
      uint4 xv = *(const uint4*)(kbuf + g);
      *(uint4*)&sX[r * 72 + c8] = xv;
      uint4 vv = *(const uint4*)(vbuf + g);
      const u16* pv = (const u16*)&vv;
#pragma unroll
      for (int j = 0; j < 8; ++j) sVT[(c8 + j) * 72 + r] = pv[j];
    }
    __syncthreads();
    {  // diag = 0.5*dn^2*sum x^2 per row
      int r = tid >> 2, qq = tid & 3;
      float s = 0;
#pragma unroll
      for (int j = 0; j < 16; ++j) { float x = bf2f(sX[r * 72 + qq * 16 + j]); s += x * x; }
      s += __shfl_xor(s, 1); s += __shfl_xor(s, 2);
      if (qq == 0) sDiag[r] = DIAGC * s;
    }
    f32x4 dacc[16] = {};
#pragma unroll
    for (int kk = 0; kk < 2; ++kk) {
      const int ko = kk * 32 + ((lane >> 4) << 3);
      bf16x8 a = *(const bf16x8*)&sX[(wv * 16 + (lane & 15)) * 72 + ko];
#pragma unroll
      for (int f = 0; f < 16; ++f) {
        bf16x8 bb = *(const bf16x8*)(projb + (f * 16 + (lane & 15)) * 64 + ko);
        dacc[f] = __builtin_amdgcn_mfma_f32_16x16x32_bf16(a, bb, dacc[f], 0, 0, 0);
      }
    }
    __syncthreads();   // sDiag ready; prev ctx-mfma long done
#pragma unroll
    for (int f = 0; f < 16; ++f) {
      float kvv[4]; float cs = 0;
#pragma unroll
      for (int r = 0; r < 4; ++r) {
        float val = RATIO * (__expf(dacc[f][r] - sDiag[row_base + r] - stab) + KEPSC);
        kvv[r] = val; cs += val;
      }
      cs += __shfl_xor(cs, 16); cs += __shfl_xor(cs, 32);
      ksacc[f] += cs;
      ushort4 pk; pk.x = f2bf(kvv[0]); pk.y = f2bf(kvv[1]); pk.z = f2bf(kvv[2]); pk.w = f2bf(kvv[3]);
      *(ushort4*)&sKpT[(f * 16 + (lane & 15)) * 72 + row_base] = pk;
    }
    __syncthreads();
#pragma unroll
    for (int kk = 0; kk < 2; ++kk) {
      const int ko = kk * 32 + ((lane >> 4) << 3);
      bf16x8 a = *(const bf16x8*)&sVT[(wv * 16 + (lane & 15)) * 72 + ko];
#pragma unroll
      for (int f = 0; f < 16; ++f) {
        bf16x8 bb = *(const bf16x8*)&sKpT[(f * 16 + (lane & 15)) * 72 + ko];
        cacc[f] = __builtin_amdgcn_mfma_f32_16x16x32_bf16(a, bb, cacc[f], 0, 0, 0);
      }
    }
  }
#pragma unroll
  for (int f = 0; f < 16; ++f) {
    const int m = f * 16 + (lane & 15);
#pragma unroll
    for (int r = 0; r < 4; ++r)
      atomicAdd(&ctxT[((size_t)bh * 64 + row_base + r) * 256 + m], cacc[f][r]);
  }
  if (lane < 16) {
#pragma unroll
    for (int f = 0; f < 16; ++f) atomicAdd(&ksum[bh * 256 + f * 16 + lane], ksacc[f]);
  }
}

// ============================================================
// query pass: qp features + d_inv + attn = (qp @ ctx) * d_inv
// ============================================================
__global__ __launch_bounds__(256, 1) void qattn_kernel(
    const u16* __restrict__ qbuf, const u16* __restrict__ projb,
    const float* __restrict__ ctxT, const float* __restrict__ ksum,
    u16* __restrict__ attnb)
{
  __shared__ __align__(16) u16 sX[64 * 72];
  __shared__ __align__(16) u16 sQp[64 * 264];
  __shared__ __align__(16) u16 sCtx[64 * 264];
  __shared__ float sKsum[256];
  __shared__ float sDiag[64];
  __shared__ float sDinv[64];
  const int tid = threadIdx.x, lane = tid & 63, wv = tid >> 6;
  const int bh = blockIdx.x, b = bh >> 4, h = bh & 15;
  const int n0 = blockIdx.y * 64;

  for (int i = tid; i < 512; i += 256) {
    int r = i >> 3, c8 = (i & 7) << 3;
    uint4 v = *(const uint4*)(qbuf + ((size_t)(b * NN + n0 + r)) * DD + h * DH + c8);
    *(uint4*)&sX[r * 72 + c8] = v;
  }
  for (int i = tid; i < 4096; i += 256) {
    int j = i >> 6, c4 = (i & 63) << 2;
    float4 cv = *(const float4*)(ctxT + ((size_t)bh * 64 + j) * 256 + c4);
    ushort4 o; o.x = f2bf(cv.x); o.y = f2bf(cv.y); o.z = f2bf(cv.z); o.w = f2bf(cv.w);
    *(ushort4*)&sCtx[j * 264 + c4] = o;
  }
  sKsum[tid] = ksum[bh * 256 + tid];
  __syncthreads();
  {
    int r = tid >> 2, qq = tid & 3;
    float s = 0;
#pragma unroll
    for (int j = 0; j < 16; ++j) { float x = bf2f(sX[r * 72 + qq * 16 + j]); s += x * x; }
    s += __shfl_xor(s, 1); s += __shfl_xor(s, 2);
    if (qq == 0) sDiag[r] = DIAGC * s;
  }
  f32x4 dacc[16] = {};
#pragma unroll
  for (int kk = 0; kk < 2; ++kk) {
    const int ko = kk * 32 + ((lane >> 4) << 3);
    bf16x8 a = *(const bf16x8*)&sX[(wv * 16 + (lane & 15)) * 72 + ko];
#pragma unroll
    for (int f = 0; f < 16; ++f) {
      bf16x8 bb = *(const bf16x8*)(projb + (f * 16 + (lane & 15)) * 64 + ko);
      dacc[f] = __builtin_amdgcn_mfma_f32_16x16x32_bf16(a, bb, dacc[f], 0, 0, 0);
    }
  }
  __syncthreads();   // sDiag ready
  const int row_base = wv * 16 + ((lane >> 4) << 2);
#pragma unroll
  for (int r = 0; r < 4; ++r) {
    const int row = row_base + r;
    float mx = dacc[0][r];
#pragma unroll
    for (int f = 1; f < 16; ++f) mx = fmaxf(mx, dacc[f][r]);
    mx = fmaxf(mx, __shfl_xor(mx, 1));
    mx = fmaxf(mx, __shfl_xor(mx, 2));
    mx = fmaxf(mx, __shfl_xor(mx, 4));
    mx = fmaxf(mx, __shfl_xor(mx, 8));
    const float dg = sDiag[row];
    float ds = 0;
#pragma unroll
    for (int f = 0; f < 16; ++f) {
      float qv = RATIO * (__expf(dacc[f][r] - dg - mx) + KEPSC);
      dacc[f][r] = qv;
      ds += qv * sKsum[f * 16 + (lane & 15)];
    }
    ds += __shfl_xor(ds, 1); ds += __shfl_xor(ds, 2);
    ds += __shfl_xor(ds, 4); ds += __shfl_xor(ds, 8);
    if ((lane & 15) == 0) sDinv[row] = 1.0f / ds;
  }
#pragma unroll
  for (int f = 0; f < 16; ++f)
#pragma unroll
    for (int r = 0; r < 4; ++r)
      sQp[(row_base + r) * 264 + f * 16 + (lane & 15)] = f2bf(dacc[f][r]);
  __syncthreads();

  const int wr = wv >> 1, wc = wv & 1;
  f32x4 acc2[2][2] = {};
#pragma unroll
  for (int kk = 0; kk < 8; ++kk) {
    const int ko = kk * 32 + ((lane >> 4) << 3);
    bf16x8 a0 = *(const bf16x8*)&sQp[(wr * 32 + (lane & 15)) * 264 + ko];
    bf16x8 a1 = *(const bf16x8*)&sQp[(wr * 32 + 16 + (lane & 15)) * 264 + ko];
    bf16x8 b0 = *(const bf16x8*)&sCtx[(wc * 32 + (lane & 15)) * 264 + ko];
    bf16x8 b1 = *(const bf16x8*)&sCtx[(wc * 32 + 16 + (lane & 15)) * 264 + ko];
    acc2[0][0] = __builtin_amdgcn_mfma_f32_16x16x32_bf16(a0, b0, acc2[0][0], 0, 0, 0);
    acc2[0][1] = __builtin_amdgcn_mfma_f32_16x16x32_bf16(a0, b1, acc2[0][1], 0, 0, 0);
    acc2[1][0] = __builtin_amdgcn_mfma_f32_16x16x32_bf16(a1, b0, acc2[1][0], 0, 0, 0);
    acc2[1][1] = __builtin_amdgcn_mfma_f32_16x16x32_bf16(a1, b1, acc2[1][1], 0, 0, 0);
  }
#pragma unroll
  for (int mi = 0; mi < 2; ++mi)
#pragma unroll
    for (int ni = 0; ni < 2; ++ni)
#pragma unroll
      for (int r = 0; r < 4; ++r) {
        const int row = wr * 32 + mi * 16 + ((lane >> 4) << 2) + r;
        const int col = wc * 32 + ni * 16 + (lane & 15);
        float v = acc2[mi][ni][r] * sDinv[row];
        attnb[((size_t)(b * NN + n0 + row)) * DD + h * DH + col] = f2bf(v);
      }
}

// ============================================================
// LayerNorms
// ============================================================
__global__ __launch_bounds__(256) void ln1_kernel(
    const float* __restrict__ y, const float* __restrict__ g,
    const float* __restrict__ be, u16* __restrict__ xb)
{
  const int row = blockIdx.x, tid = threadIdx.x;
  const float4 v = ((const float4*)(y + (size_t)row * DD))[tid];
  float s = v.x + v.y + v.z + v.w;
  float ss = v.x * v.x + v.y * v.y + v.z * v.z + v.w * v.w;
#pragma unroll
  for (int m = 1; m < 64; m <<= 1) { s += __shfl_xor(s, m); ss += __shfl_xor(ss, m); }
  __shared__ float red[8];
  if ((tid & 63) == 0) { red[tid >> 6] = s; red[4 + (tid >> 6)] = ss; }
  __syncthreads();
  s = red[0] + red[1] + red[2] + red[3];
  ss = red[4] + red[5] + red[6] + red[7];
  const float mu = s * (1.0f / DD);
  const float rs = rsqrtf(ss * (1.0f / DD) - mu * mu + 1e-5f);
  const float4 gv = ((const float4*)g)[tid];
  const float4 bv = ((const float4*)be)[tid];
  ushort4 o;
  o.x = f2bf((v.x - mu) * rs * gv.x + bv.x);
  o.y = f2bf((v.y - mu) * rs * gv.y + bv.y);
  o.z = f2bf((v.z - mu) * rs * gv.z + bv.z);
  o.w = f2bf((v.w - mu) * rs * gv.w + bv.w);
  ((ushort4*)(xb + (size_t)row * DD))[tid] = o;
}

__global__ __launch_bounds__(256) void ln2_kernel(
    const u16* __restrict__ xb, const u16* __restrict__ ff,
    const float* __restrict__ g, const float* __restrict__ be, float* __restrict__ out)
{
  const int row = blockIdx.x, tid = threadIdx.x;
  const ushort4 xv = ((const ushort4*)(xb + (size_t)row * DD))[tid];
  const ushort4 fv = ((const ushort4*)(ff + (size_t)row * DD))[tid];
  float x0 = bf2f(xv.x) + bf2f(fv.x);
  float x1 = bf2f(xv.y) + bf2f(fv.y);
  float x2 = bf2f(xv.z) + bf2f(fv.z);
  float x3 = bf2f(xv.w) + bf2f(fv.w);
  float s = x0 + x1 + x2 + x3;
  float ss = x0 * x0 + x1 * x1 + x2 * x2 + x3 * x3;
#pragma unroll
  for (int m = 1; m < 64; m <<= 1) { s += __shfl_xor(s, m); ss += __shfl_xor(ss, m); }
  __shared__ float red[8];
  if ((tid & 63) == 0) { red[tid >> 6] = s; red[4 + (tid >> 6)] = ss; }
  __syncthreads();
  s = red[0] + red[1] + red[2] + red[3];
  ss = red[4] + red[5] + red[6] + red[7];
  const float mu = s * (1.0f / DD);
  const float rs = rsqrtf(ss * (1.0f / DD) - mu * mu + 1e-5f);
  const float4 gv = ((const float4*)g)[tid];
  const float4 bv = ((const float4*)be)[tid];
  float4 o;
  o.x = (x0 - mu) * rs * gv.x + bv.x;
  o.y = (x1 - mu) * rs * gv.y + bv.y;
  o.z = (x2 - mu) * rs * gv.z + bv.z;
  o.w = (x3 - mu) * rs * gv.w + bv.w;
  ((float4*)(out + (size_t)row * DD))[tid] = o;
}

// ============================================================
// launch
// ============================================================
extern "C" void kernel_launch(void* const* d_in, const int* in_sizes, int n_in,
                              void* d_out, int out_size, void* d_ws, size_t ws_size,
                              hipStream_t stream) {
  (void)in_sizes; (void)n_in; (void)out_size; (void)ws_size;
  const float* src   = (const float*)d_in[0];
  const float* Wq    = (const float*)d_in[1];
  const float* Wk    = (const float*)d_in[2];
  const float* Wv    = (const float*)d_in[3];
  const float* Wout  = (const float*)d_in[4];
  const float* b_out = (const float*)d_in[5];
  const float* proj  = (const float*)d_in[6];
  const float* g1    = (const float*)d_in[7];
  const float* be1   = (const float*)d_in[8];
  const float* W1    = (const float*)d_in[9];
  const float* b1    = (const float*)d_in[10];
  const float* W2    = (const float*)d_in[11];
  const float* b2    = (const float*)d_in[12];
  const float* g2    = (const float*)d_in[13];
  const float* be2   = (const float*)d_in[14];

  char* ws = (char*)d_ws;
  // layout (bytes); aliases documented inline
  constexpr size_t OFF_SRCB = 0;                 // 33.5MB  [+qb = ybuf f32 / h1 bf16]
  constexpr size_t OFF_QB   = 33554432;
  constexpr size_t OFF_VB   = 67108864;          // later: xb bf16
  constexpr size_t OFF_KB   = 100663296;         // later: attn bf16, then ff bf16
  constexpr size_t OFF_WQ   = 134217728;
  constexpr size_t OFF_WK   = 136314880;
  constexpr size_t OFF_WV   = 138412032;
  constexpr size_t OFF_WO   = 140509184;
  constexpr size_t OFF_W1   = 142606336;
  constexpr size_t OFF_W2   = 146800640;
  constexpr size_t OFF_PROJ = 150994944;
  constexpr size_t OFF_CTXT = 151027712;         // 4MB f32
  constexpr size_t OFF_KSUM = 155222016;         // 64KB f32
  constexpr size_t OFF_STAB = 155287552;         // 4B (mapped uint)

  u16* srcb  = (u16*)(ws + OFF_SRCB);
  u16* qb    = (u16*)(ws + OFF_QB);
  u16* vb    = (u16*)(ws + OFF_VB);
  u16* kb    = (u16*)(ws + OFF_KB);
  u16* wqb   = (u16*)(ws + OFF_WQ);
  u16* wkb   = (u16*)(ws + OFF_WK);
  u16* wvb   = (u16*)(ws + OFF_WV);
  u16* wob   = (u16*)(ws + OFF_WO);
  u16* w1b   = (u16*)(ws + OFF_W1);
  u16* w2b   = (u16*)(ws + OFF_W2);
  u16* projb = (u16*)(ws + OFF_PROJ);
  float* ctxT = (float*)(ws + OFF_CTXT);
  float* ksum = (float*)(ws + OFF_KSUM);
  u32*  stab  = (u32*)(ws + OFF_STAB);
  float* ybuf = (float*)(ws + OFF_SRCB);   // alias srcb+qb (dead then)
  u16* attnb  = kb;                        // alias kb (dead then)
  u16* xb     = vb;                        // alias vb (dead then)
  u16* h1     = (u16*)(ws + OFF_SRCB);     // alias ybuf (dead then)
  u16* ff     = kb;                        // alias attn (dead then)

  // casts
  cast_kernel<<<4096, 256, 0, stream>>>(src, srcb, RT * DD / 4);
  cast_kernel<<<1024, 256, 0, stream>>>(Wq, wqb, DD * DD / 4);
  cast_kernel<<<1024, 256, 0, stream>>>(Wk, wkb, DD * DD / 4);
  cast_kernel<<<1024, 256, 0, stream>>>(Wv, wvb, DD * DD / 4);
  cast_kernel<<<1024, 256, 0, stream>>>(Wout, wob, DD * DD / 4);
  cast_kernel<<<2048, 256, 0, stream>>>(W1, w1b, 2048 * DD / 4);
  cast_kernel<<<2048, 256, 0, stream>>>(W2, w2b, 2048 * DD / 4);
  cast_proj_kernel<<<16, 256, 0, stream>>>(proj, projb);
  hipMemsetAsync(ws + OFF_CTXT, 0, 4194304 + 65536 + 256, stream);

  // QKV projections
  dim3 gqkv(DD / 128, RT / 128);
  gemm_bt<0><<<gqkv, 256, 0, stream>>>(srcb, wqb, qb, nullptr, nullptr, nullptr, RT, DD, DD);
  gemm_bt<0><<<gqkv, 256, 0, stream>>>(srcb, wkb, kb, nullptr, nullptr, nullptr, RT, DD, DD);
  gemm_bt<0><<<gqkv, 256, 0, stream>>>(srcb, wvb, vb, nullptr, nullptr, nullptr, RT, DD, DD);

  // performer features
  kmax_kernel<<<dim3(64, 64), 256, 0, stream>>>(kb, projb, stab);
  kctx_kernel<<<dim3(64, 4), 256, 0, stream>>>(kb, vb, projb, stab, ctxT, ksum);
  qattn_kernel<<<dim3(64, 64), 256, 0, stream>>>(qb, projb, ctxT, ksum, attnb);

  // Wout + residual, LN1
  gemm_bt<1><<<gqkv, 256, 0, stream>>>(attnb, wob, nullptr, ybuf, b_out, src, RT, DD, DD);
  ln1_kernel<<<RT, 256, 0, stream>>>(ybuf, g1, be1, xb);

  // FFN
  gemm_bt<2><<<dim3(2048 / 128, RT / 128), 256, 0, stream>>>(xb, w1b, h1, nullptr, b1, nullptr, RT, 2048, DD);
  gemm_bt<3><<<dim3(DD / 128, RT / 128), 256, 0, stream>>>(h1, w2b, ff, nullptr, b2, nullptr, RT, DD, 2048);
  ln2_kernel<<<RT, 256, 0, stream>>>(xb, ff, g2, be2, (float*)d_out);
}

// Round 2
// 918.789 us; speedup vs baseline: 1.1034x; 1.1034x over previous
//
#include <hip/hip_runtime.h>

#define DEVI __device__ __forceinline__

using u16 = unsigned short;
using u32 = unsigned int;
using u64 = unsigned long long;

typedef __bf16 bf16x8 __attribute__((ext_vector_type(8)));
typedef float  f32x4  __attribute__((ext_vector_type(4)));

constexpr int BB = 4, NN = 4096, DD = 1024, HH = 16, DH = 64, MF = 256;
constexpr int RT = BB * NN;                       // 16384 rows total
constexpr float DN    = 0.35355339059327373f;     // 64^-0.25
constexpr float RATIO = 0.0625f;                  // 256^-0.5
constexpr float DIAGC = 0.0625f;                  // 0.5 * DN^2
constexpr float KEPSC = 1e-3f;

// ---------- scalar helpers ----------
DEVI u16 f2bf(float f) {
  u32 u = __float_as_uint(f);
  u32 r = u + 0x7fffu + ((u >> 16) & 1u);   // RNE
  return (u16)(r >> 16);
}
DEVI float bf2f(u16 u) { return __uint_as_float(((u32)u) << 16); }

// ---------- global_load_lds (CK addrspace pattern) ----------
typedef void __attribute__((address_space(1)))* gas1;
typedef void __attribute__((address_space(3)))* las3;
DEVI void gload_lds16(const void* g, void* l) {
  __builtin_amdgcn_global_load_lds((gas1)(u64)g, (las3)(u32)(u64)l, 16, 0, 0);
}

// swizzled fragment read from a [128][64]-bf16 LDS tile (row stride 128B)
DEVI bf16x8 ldswz(const u16* base, int row, int kbyte) {
  int p = (row << 7) + kbyte;
  p ^= (row & 7) << 4;                      // same involution as the staging side
  return *(const bf16x8*)((const char*)base + p);
}

// ============================================================
// casts
// ============================================================
__global__ void cast_kernel(const float* __restrict__ in, u16* __restrict__ out, int n4) {
  int i = blockIdx.x * 256 + threadIdx.x;
  int stride = gridDim.x * 256;
  for (; i < n4; i += stride) {
    float4 v = ((const float4*)in)[i];
    ushort4 o; o.x = f2bf(v.x); o.y = f2bf(v.y); o.z = f2bf(v.z); o.w = f2bf(v.w);
    ((ushort4*)out)[i] = o;
  }
}

__global__ void cast_proj_kernel(const float* __restrict__ in, u16* __restrict__ out) {
  int i = blockIdx.x * 256 + threadIdx.x;   // 4096 threads, 16384 elems
  float4 v = ((const float4*)in)[i];
  ushort4 o; o.x = f2bf(v.x * DN); o.y = f2bf(v.y * DN); o.z = f2bf(v.z * DN); o.w = f2bf(v.w * DN);
  ((ushort4*)out)[i] = o;
}

// ============================================================
// GEMM: C[i,j] = sum_k A[i,k] * B[j,k]   (both K-contiguous, bf16)
// 128x128 tile, BK=64, 4 waves (2x2), 16x16x32 MFMA, gload_lds + XOR swizzle
// EPI 0: C->bf16 | 1: +bias+add32 -> f32 | 2: +bias, gelu -> bf16 | 3: +bias -> bf16
// ============================================================
template <int EPI>
__global__ __launch_bounds__(256, 2) void gemm_bt(
    const u16* __restrict__ A, const u16* __restrict__ Bm,
    u16* __restrict__ Cb, float* __restrict__ Cf,
    const float* __restrict__ bias, const float* __restrict__ add32,
    int M, int Ncols, int K)
{
  __shared__ __align__(16) u16 sA[128 * 64];
  __shared__ __align__(16) u16 sB[128 * 64];
  const int tid = threadIdx.x, lane = tid & 63;
  const int wv = tid >> 6, wr = wv >> 1, wc = wv & 1;
  const int bm = blockIdx.y, bn = blockIdx.x;

  f32x4 acc[4][4] = {};

  int rowS[4], colS[4], ldsb[4];
#pragma unroll
  for (int it = 0; it < 4; ++it) {
    int p = (it * 256 + tid) * 16;                // linear LDS byte this lane fills
    ldsb[it] = (it * 256 + (tid & ~63)) * 16;     // wave-uniform base
    int sp = p ^ (((p >> 7) & 7) << 4);           // inverse-swizzled source position
    rowS[it] = sp >> 7;
    colS[it] = (sp >> 1) & 63;
  }
  const size_t baseA = (size_t)bm * 128, baseB = (size_t)bn * 128;

  for (int kt = 0; kt < K; kt += 64) {
#pragma unroll
    for (int it = 0; it < 4; ++it)
      gload_lds16(A + (baseA + rowS[it]) * K + kt + colS[it], (char*)sA + ldsb[it]);
#pragma unroll
    for (int it = 0; it < 4; ++it)
      gload_lds16(Bm + (baseB + rowS[it]) * K + kt + colS[it], (char*)sB + ldsb[it]);
    __syncthreads();
#pragma unroll
    for (int kk = 0; kk < 2; ++kk) {
      const int kbyte = kk * 64 + ((lane >> 4) << 4);
      bf16x8 a[4], b[4];
#pragma unroll
      for (int i = 0; i < 4; ++i) a[i] = ldswz(sA, wr * 64 + i * 16 + (lane & 15), kbyte);
#pragma unroll
      for (int i = 0; i < 4; ++i) b[i] = ldswz(sB, wc * 64 + i * 16 + (lane & 15), kbyte);
#pragma unroll
      for (int i = 0; i < 4; ++i)
#pragma unroll
        for (int j = 0; j < 4; ++j)
          acc[i][j] = __builtin_amdgcn_mfma_f32_16x16x32_bf16(a[i], b[j], acc[i][j], 0, 0, 0);
    }
    __syncthreads();
  }

#pragma unroll
  for (int i = 0; i < 4; ++i) {
    const int gr0 = bm * 128 + wr * 64 + i * 16 + ((lane >> 4) << 2);
#pragma unroll
    for (int j = 0; j < 4; ++j) {
      const int gc = bn * 128 + wc * 64 + j * 16 + (lane & 15);
#pragma unroll
      for (int r = 0; r < 4; ++r) {
        const size_t o = (size_t)(gr0 + r) * Ncols + gc;
        const float v = acc[i][j][r];
        if constexpr (EPI == 0) {
          Cb[o] = f2bf(v);
        } else if constexpr (EPI == 1) {
          Cf[o] = v + bias[gc] + add32[o];
        } else if constexpr (EPI == 2) {
          float t = v + bias[gc];
          Cb[o] = f2bf(0.5f * t * (1.0f + erff(t * 0.70710678118654752f)));
        } else {
          Cb[o] = f2bf(v + bias[gc]);
        }
      }
    }
  }
}

// ============================================================
// key pass 1: per-block max of data_dash -> pmax[block] (no contended atomics)
// ============================================================
__global__ __launch_bounds__(256) void kmax_kernel(
    const u16* __restrict__ kbuf, const u16* __restrict__ projb, float* __restrict__ pmax)
{
  __shared__ __align__(16) u16 sX[64 * 72];
  __shared__ float sred[4];
  const int tid = threadIdx.x, lane = tid & 63, wv = tid >> 6;
  const int bh = blockIdx.x, b = bh >> 4, h = bh & 15;
  const int n0 = blockIdx.y * 64;

  for (int i = tid; i < 512; i += 256) {
    int r = i >> 3, c8 = (i & 7) << 3;
    uint4 v = *(const uint4*)(kbuf + ((size_t)(b * NN + n0 + r)) * DD + h * DH + c8);
    *(uint4*)&sX[r * 72 + c8] = v;
  }
  __syncthreads();

  f32x4 dacc[16] = {};
#pragma unroll
  for (int kk = 0; kk < 2; ++kk) {
    const int ko = kk * 32 + ((lane >> 4) << 3);
    bf16x8 a = *(const bf16x8*)&sX[(wv * 16 + (lane & 15)) * 72 + ko];
#pragma unroll
    for (int f = 0; f < 16; ++f) {
      bf16x8 bb = *(const bf16x8*)(projb + (f * 16 + (lane & 15)) * 64 + ko);
      dacc[f] = __builtin_amdgcn_mfma_f32_16x16x32_bf16(a, bb, dacc[f], 0, 0, 0);
    }
  }
  float mx = -1e30f;
#pragma unroll
  for (int f = 0; f < 16; ++f)
#pragma unroll
    for (int r = 0; r < 4; ++r) mx = fmaxf(mx, dacc[f][r]);
#pragma unroll
  for (int m = 1; m < 64; m <<= 1) mx = fmaxf(mx, __shfl_xor(mx, m));
  if (lane == 0) sred[wv] = mx;
  __syncthreads();
  if (tid == 0)
    pmax[blockIdx.y * gridDim.x + blockIdx.x] =
        fmaxf(fmaxf(sred[0], sred[1]), fmaxf(sred[2], sred[3]));
}

// second stage: 4096 partial maxes -> stab[0]
__global__ __launch_bounds__(256) void reduce_max_kernel(
    const float* __restrict__ pmax, float* __restrict__ stab)
{
  const int tid = threadIdx.x;
  float mx = -1e30f;
#pragma unroll
  for (int i = 0; i < 16; ++i) mx = fmaxf(mx, pmax[i * 256 + tid]);
#pragma unroll
  for (int m = 1; m < 64; m <<= 1) mx = fmaxf(mx, __shfl_xor(mx, m));
  __shared__ float sred[4];
  if ((tid & 63) == 0) sred[tid >> 6] = mx;
  __syncthreads();
  if (tid == 0)
    stab[0] = fmaxf(fmaxf(sred[0], sred[1]), fmaxf(sred[2], sred[3]));
}

// ============================================================
// key pass 2: kp -> k_sum[m], ctxT[j,m] += sum_n v[n,j]*kp[n,m]
// ============================================================
__global__ __launch_bounds__(256, 1) void kctx_kernel(
    const u16* __restrict__ kbuf, const u16* __restrict__ vbuf,
    const u16* __restrict__ projb, const float* __restrict__ stab_p,
    float* __restrict__ ctxT, float* __restrict__ ksum)
{
  __shared__ __align__(16) u16 sX[64 * 72];
  __shared__ __align__(16) u16 sVT[64 * 72];
  __shared__ __align__(16) u16 sKpT[256 * 72];
  __shared__ float sDiag[64];
  const int tid = threadIdx.x, lane = tid & 63, wv = tid >> 6;
  const int bh = blockIdx.x, b = bh >> 4, h = bh & 15;
  const float stab = stab_p[0];

  f32x4 cacc[16] = {};
  float ksacc[16] = {};
  const int row_base = wv * 16 + ((lane >> 4) << 2);

  for (int t = 0; t < 8; ++t) {
    const int n0 = blockIdx.y * 512 + t * 64;
    if (t) __syncthreads();
    for (int i = tid; i < 512; i += 256) {
      int r = i >> 3, c8 = (i & 7) << 3;
      size_t g = ((size_t)(b * NN + n0 + r)) * DD + h * DH + c8;
      uint4 xv = *(const uint4*)(kbuf + g);
      *(uint4*)&sX[r * 72 + c8] = xv;
      uint4 vv = *(const uint4*)(vbuf + g);
      const u16* pv = (const u16*)&vv;
#pragma unroll
      for (int j = 0; j < 8; ++j) sVT[(c8 + j) * 72 + r] = pv[j];
    }
    __syncthreads();
    {  // diag = 0.5*dn^2*sum x^2 per row
      int r = tid >> 2, qq = tid & 3;
      float s = 0;
#pragma unroll
      for (int j = 0; j < 16; ++j) { float x = bf2f(sX[r * 72 + qq * 16 + j]); s += x * x; }
      s += __shfl_xor(s, 1); s += __shfl_xor(s, 2);
      if (qq == 0) sDiag[r] = DIAGC * s;
    }
    f32x4 dacc[16] = {};
#pragma unroll
    for (int kk = 0; kk < 2; ++kk) {
      const int ko = kk * 32 + ((lane >> 4) << 3);
      bf16x8 a = *(const bf16x8*)&sX[(wv * 16 + (lane & 15)) * 72 + ko];
#pragma unroll
      for (int f = 0; f < 16; ++f) {
        bf16x8 bb = *(const bf16x8*)(projb + (f * 16 + (lane & 15)) * 64 + ko);
        dacc[f] = __builtin_amdgcn_mfma_f32_16x16x32_bf16(a, bb, dacc[f], 0, 0, 0);
      }
    }
    __syncthreads();   // sDiag ready; prev ctx-mfma long done
#pragma unroll
    for (int f = 0; f < 16; ++f) {
      float kvv[4]; float cs = 0;
#pragma unroll
      for (int r = 0; r < 4; ++r) {
        float val = RATIO * (__expf(dacc[f][r] - sDiag[row_base + r] - stab) + KEPSC);
        kvv[r] = val; cs += val;
      }
      cs += __shfl_xor(cs, 16); cs += __shfl_xor(cs, 32);
      ksacc[f] += cs;
      ushort4 pk; pk.x = f2bf(kvv[0]); pk.y = f2bf(kvv[1]); pk.z = f2bf(kvv[2]); pk.w = f2bf(kvv[3]);
      *(ushort4*)&sKpT[(f * 16 + (lane & 15)) * 72 + row_base] = pk;
    }
    __syncthreads();
#pragma unroll
    for (int kk = 0; kk < 2; ++kk) {
      const int ko = kk * 32 + ((lane >> 4) << 3);
      bf16x8 a = *(const bf16x8*)&sVT[(wv * 16 + (lane & 15)) * 72 + ko];
#pragma unroll
      for (int f = 0; f < 16; ++f) {
        bf16x8 bb = *(const bf16x8*)&sKpT[(f * 16 + (lane & 15)) * 72 + ko];
        cacc[f] = __builtin_amdgcn_mfma_f32_16x16x32_bf16(a, bb, cacc[f], 0, 0, 0);
      }
    }
  }
#pragma unroll
  for (int f = 0; f < 16; ++f) {
    const int m = f * 16 + (lane & 15);
#pragma unroll
    for (int r = 0; r < 4; ++r)
      atomicAdd(&ctxT[((size_t)bh * 64 + row_base + r) * 256 + m], cacc[f][r]);
  }
  if (lane < 16) {
#pragma unroll
    for (int f = 0; f < 16; ++f) atomicAdd(&ksum[bh * 256 + f * 16 + lane], ksacc[f]);
  }
}

// ============================================================
// query pass: qp features + d_inv + attn = (qp @ ctx) * d_inv
// ============================================================
__global__ __launch_bounds__(256, 1) void qattn_kernel(
    const u16* __restrict__ qbuf, const u16* __restrict__ projb,
    const float* __restrict__ ctxT, const float* __restrict__ ksum,
    u16* __restrict__ attnb)
{
  __shared__ __align__(16) u16 sX[64 * 72];
  __shared__ __align__(16) u16 sQp[64 * 264];
  __shared__ __align__(16) u16 sCtx[64 * 264];
  __shared__ float sKsum[256];
  __shared__ float sDiag[64];
  __shared__ float sDinv[64];
  const int tid = threadIdx.x, lane = tid & 63, wv = tid >> 6;
  const int bh = blockIdx.x, b = bh >> 4, h = bh & 15;
  const int n0 = blockIdx.y * 64;

  for (int i = tid; i < 512; i += 256) {
    int r = i >> 3, c8 = (i & 7) << 3;
    uint4 v = *(const uint4*)(qbuf + ((size_t)(b * NN + n0 + r)) * DD + h * DH + c8);
    *(uint4*)&sX[r * 72 + c8] = v;
  }
  for (int i = tid; i < 4096; i += 256) {
    int j = i >> 6, c4 = (i & 63) << 2;
    float4 cv = *(const float4*)(ctxT + ((size_t)bh * 64 + j) * 256 + c4);
    ushort4 o; o.x = f2bf(cv.x); o.y = f2bf(cv.y); o.z = f2bf(cv.z); o.w = f2bf(cv.w);
    *(ushort4*)&sCtx[j * 264 + c4] = o;
  }
  sKsum[tid] = ksum[bh * 256 + tid];
  __syncthreads();
  {
    int r = tid >> 2, qq = tid & 3;
    float s = 0;
#pragma unroll
    for (int j = 0; j < 16; ++j) { float x = bf2f(sX[r * 72 + qq * 16 + j]); s += x * x; }
    s += __shfl_xor(s, 1); s += __shfl_xor(s, 2);
    if (qq == 0) sDiag[r] = DIAGC * s;
  }
  f32x4 dacc[16] = {};
#pragma unroll
  for (int kk = 0; kk < 2; ++kk) {
    const int ko = kk * 32 + ((lane >> 4) << 3);
    bf16x8 a = *(const bf16x8*)&sX[(wv * 16 + (lane & 15)) * 72 + ko];
#pragma unroll
    for (int f = 0; f < 16; ++f) {
      bf16x8 bb = *(const bf16x8*)(projb + (f * 16 + (lane & 15)) * 64 + ko);
      dacc[f] = __builtin_amdgcn_mfma_f32_16x16x32_bf16(a, bb, dacc[f], 0, 0, 0);
    }
  }
  __syncthreads();   // sDiag ready
  const int row_base = wv * 16 + ((lane >> 4) << 2);
#pragma unroll
  for (int r = 0; r < 4; ++r) {
    const int row = row_base + r;
    float mx = dacc[0][r];
#pragma unroll
    for (int f = 1; f < 16; ++f) mx = fmaxf(mx, dacc[f][r]);
    mx = fmaxf(mx, __shfl_xor(mx, 1));
    mx = fmaxf(mx, __shfl_xor(mx, 2));
    mx = fmaxf(mx, __shfl_xor(mx, 4));
    mx = fmaxf(mx, __shfl_xor(mx, 8));
    const float dg = sDiag[row];
    float ds = 0;
#pragma unroll
    for (int f = 0; f < 16; ++f) {
      float qv = RATIO * (__expf(dacc[f][r] - dg - mx) + KEPSC);
      dacc[f][r] = qv;
      ds += qv * sKsum[f * 16 + (lane & 15)];
    }
    ds += __shfl_xor(ds, 1); ds += __shfl_xor(ds, 2);
    ds += __shfl_xor(ds, 4); ds += __shfl_xor(ds, 8);
    if ((lane & 15) == 0) sDinv[row] = 1.0f / ds;
  }
#pragma unroll
  for (int f = 0; f < 16; ++f)
#pragma unroll
    for (int r = 0; r < 4; ++r)
      sQp[(row_base + r) * 264 + f * 16 + (lane & 15)] = f2bf(dacc[f][r]);
  __syncthreads();

  const int wr = wv >> 1, wc = wv & 1;
  f32x4 acc2[2][2] = {};
#pragma unroll
  for (int kk = 0; kk < 8; ++kk) {
    const int ko = kk * 32 + ((lane >> 4) << 3);
    bf16x8 a0 = *(const bf16x8*)&sQp[(wr * 32 + (lane & 15)) * 264 + ko];
    bf16x8 a1 = *(const bf16x8*)&sQp[(wr * 32 + 16 + (lane & 15)) * 264 + ko];
    bf16x8 b0 = *(const bf16x8*)&sCtx[(wc * 32 + (lane & 15)) * 264 + ko];
    bf16x8 b1 = *(const bf16x8*)&sCtx[(wc * 32 + 16 + (lane & 15)) * 264 + ko];
    acc2[0][0] = __builtin_amdgcn_mfma_f32_16x16x32_bf16(a0, b0, acc2[0][0], 0, 0, 0);
    acc2[0][1] = __builtin_amdgcn_mfma_f32_16x16x32_bf16(a0, b1, acc2[0][1], 0, 0, 0);
    acc2[1][0] = __builtin_amdgcn_mfma_f32_16x16x32_bf16(a1, b0, acc2[1][0], 0, 0, 0);
    acc2[1][1] = __builtin_amdgcn_mfma_f32_16x16x32_bf16(a1, b1, acc2[1][1], 0, 0, 0);
  }
#pragma unroll
  for (int mi = 0; mi < 2; ++mi)
#pragma unroll
    for (int ni = 0; ni < 2; ++ni)
#pragma unroll
      for (int r = 0; r < 4; ++r) {
        const int row = wr * 32 + mi * 16 + ((lane >> 4) << 2) + r;
        const int col = wc * 32 + ni * 16 + (lane & 15);
        float v = acc2[mi][ni][r] * sDinv[row];
        attnb[((size_t)(b * NN + n0 + row)) * DD + h * DH + col] = f2bf(v);
      }
}

// ============================================================
// LayerNorms
// ============================================================
__global__ __launch_bounds__(256) void ln1_kernel(
    const float* __restrict__ y, const float* __restrict__ g,
    const float* __restrict__ be, u16* __restrict__ xb)
{
  const int row = blockIdx.x, tid = threadIdx.x;
  const float4 v = ((const float4*)(y + (size_t)row * DD))[tid];
  float s = v.x + v.y + v.z + v.w;
  float ss = v.x * v.x + v.y * v.y + v.z * v.z + v.w * v.w;
#pragma unroll
  for (int m = 1; m < 64; m <<= 1) { s += __shfl_xor(s, m); ss += __shfl_xor(ss, m); }
  __shared__ float red[8];
  if ((tid & 63) == 0) { red[tid >> 6] = s; red[4 + (tid >> 6)] = ss; }
  __syncthreads();
  s = red[0] + red[1] + red[2] + red[3];
  ss = red[4] + red[5] + red[6] + red[7];
  const float mu = s * (1.0f / DD);
  const float rs = rsqrtf(ss * (1.0f / DD) - mu * mu + 1e-5f);
  const float4 gv = ((const float4*)g)[tid];
  const float4 bv = ((const float4*)be)[tid];
  ushort4 o;
  o.x = f2bf((v.x - mu) * rs * gv.x + bv.x);
  o.y = f2bf((v.y - mu) * rs * gv.y + bv.y);
  o.z = f2bf((v.z - mu) * rs * gv.z + bv.z);
  o.w = f2bf((v.w - mu) * rs * gv.w + bv.w);
  ((ushort4*)(xb + (size_t)row * DD))[tid] = o;
}

__global__ __launch_bounds__(256) void ln2_kernel(
    const u16* __restrict__ xb, const u16* __restrict__ ff,
    const float* __restrict__ g, const float* __restrict__ be, float* __restrict__ out)
{
  const int row = blockIdx.x, tid = threadIdx.x;
  const ushort4 xv = ((const ushort4*)(xb + (size_t)row * DD))[tid];
  const ushort4 fv = ((const ushort4*)(ff + (size_t)row * DD))[tid];
  float x0 = bf2f(xv.x) + bf2f(fv.x);
  float x1 = bf2f(xv.y) + bf2f(fv.y);
  float x2 = bf2f(xv.z) + bf2f(fv.z);
  float x3 = bf2f(xv.w) + bf2f(fv.w);
  float s = x0 + x1 + x2 + x3;
  float ss = x0 * x0 + x1 * x1 + x2 * x2 + x3 * x3;
#pragma unroll
  for (int m = 1; m < 64; m <<= 1) { s += __shfl_xor(s, m); ss += __shfl_xor(ss, m); }
  __shared__ float red[8];
  if ((tid & 63) == 0) { red[tid >> 6] = s; red[4 + (tid >> 6)] = ss; }
  __syncthreads();
  s = red[0] + red[1] + red[2] + red[3];
  ss = red[4] + red[5] + red[6] + red[7];
  const float mu = s * (1.0f / DD);
  const float rs = rsqrtf(ss * (1.0f / DD) - mu * mu + 1e-5f);
  const float4 gv = ((const float4*)g)[tid];
  const float4 bv = ((const float4*)be)[tid];
  float4 o;
  o.x = (x0 - mu) * rs * gv.x + bv.x;
  o.y = (x1 - mu) * rs * gv.y + bv.y;
  o.z = (x2 - mu) * rs * gv.z + bv.z;
  o.w = (x3 - mu) * rs * gv.w + bv.w;
  ((float4*)(out + (size_t)row * DD))[tid] = o;
}

// ============================================================
// launch
// ============================================================
extern "C" void kernel_launch(void* const* d_in, const int* in_sizes, int n_in,
                              void* d_out, int out_size, void* d_ws, size_t ws_size,
                              hipStream_t stream) {
  (void)in_sizes; (void)n_in; (void)out_size; (void)ws_size;
  const float* src   = (const float*)d_in[0];
  const float* Wq    = (const float*)d_in[1];
  const float* Wk    = (const float*)d_in[2];
  const float* Wv    = (const float*)d_in[3];
  const float* Wout  = (const float*)d_in[4];
  const float* b_out = (const float*)d_in[5];
  const float* proj  = (const float*)d_in[6];
  const float* g1    = (const float*)d_in[7];
  const float* be1   = (const float*)d_in[8];
  const float* W1    = (const float*)d_in[9];
  const float* b1    = (const float*)d_in[10];
  const float* W2    = (const float*)d_in[11];
  const float* b2    = (const float*)d_in[12];
  const float* g2    = (const float*)d_in[13];
  const float* be2   = (const float*)d_in[14];

  char* ws = (char*)d_ws;
  // layout (bytes); aliases documented inline
  constexpr size_t OFF_SRCB = 0;                 // 33.5MB  [+qb = ybuf f32 / h1 bf16]
  constexpr size_t OFF_QB   = 33554432;
  constexpr size_t OFF_VB   = 67108864;          // later: xb bf16
  constexpr size_t OFF_KB   = 100663296;         // later: attn bf16, then ff bf16
  constexpr size_t OFF_WQ   = 134217728;
  constexpr size_t OFF_WK   = 136314880;
  constexpr size_t OFF_WV   = 138412032;
  constexpr size_t OFF_WO   = 140509184;
  constexpr size_t OFF_W1   = 142606336;
  constexpr size_t OFF_W2   = 146800640;
  constexpr size_t OFF_PROJ = 150994944;
  constexpr size_t OFF_CTXT = 151027712;         // 4MB f32
  constexpr size_t OFF_KSUM = 155222016;         // 64KB f32
  constexpr size_t OFF_STAB = 155287552;         // 4B float
  constexpr size_t OFF_PMAX = 155291648;         // 16KB f32 (4096 block maxes)

  u16* srcb  = (u16*)(ws + OFF_SRCB);
  u16* qb    = (u16*)(ws + OFF_QB);
  u16* vb    = (u16*)(ws + OFF_VB);
  u16* kb    = (u16*)(ws + OFF_KB);
  u16* wqb   = (u16*)(ws + OFF_WQ);
  u16* wkb   = (u16*)(ws + OFF_WK);
  u16* wvb   = (u16*)(ws + OFF_WV);
  u16* wob   = (u16*)(ws + OFF_WO);
  u16* w1b   = (u16*)(ws + OFF_W1);
  u16* w2b   = (u16*)(ws + OFF_W2);
  u16* projb = (u16*)(ws + OFF_PROJ);
  float* ctxT = (float*)(ws + OFF_CTXT);
  float* ksum = (float*)(ws + OFF_KSUM);
  float* stab = (float*)(ws + OFF_STAB);
  float* pmax = (float*)(ws + OFF_PMAX);
  float* ybuf = (float*)(ws + OFF_SRCB);   // alias srcb+qb (dead then)
  u16* attnb  = kb;                        // alias kb (dead then)
  u16* xb     = vb;                        // alias vb (dead then)
  u16* h1     = (u16*)(ws + OFF_SRCB);     // alias ybuf (dead then)
  u16* ff     = kb;                        // alias attn (dead then)

  // casts
  cast_kernel<<<4096, 256, 0, stream>>>(src, srcb, RT * DD / 4);
  cast_kernel<<<1024, 256, 0, stream>>>(Wq, wqb, DD * DD / 4);
  cast_kernel<<<1024, 256, 0, stream>>>(Wk, wkb, DD * DD / 4);
  cast_kernel<<<1024, 256, 0, stream>>>(Wv, wvb, DD * DD / 4);
  cast_kernel<<<1024, 256, 0, stream>>>(Wout, wob, DD * DD / 4);
  cast_kernel<<<2048, 256, 0, stream>>>(W1, w1b, 2048 * DD / 4);
  cast_kernel<<<2048, 256, 0, stream>>>(W2, w2b, 2048 * DD / 4);
  cast_proj_kernel<<<16, 256, 0, stream>>>(proj, projb);
  hipMemsetAsync(ws + OFF_CTXT, 0, 4194304 + 65536 + 256, stream);

  // QKV projections
  dim3 gqkv(DD / 128, RT / 128);
  gemm_bt<0><<<gqkv, 256, 0, stream>>>(srcb, wqb, qb, nullptr, nullptr, nullptr, RT, DD, DD);
  gemm_bt<0><<<gqkv, 256, 0, stream>>>(srcb, wkb, kb, nullptr, nullptr, nullptr, RT, DD, DD);
  gemm_bt<0><<<gqkv, 256, 0, stream>>>(srcb, wvb, vb, nullptr, nullptr, nullptr, RT, DD, DD);

  // performer features
  kmax_kernel<<<dim3(64, 64), 256, 0, stream>>>(kb, projb, pmax);
  reduce_max_kernel<<<1, 256, 0, stream>>>(pmax, stab);
  kctx_kernel<<<dim3(64, 8), 256, 0, stream>>>(kb, vb, projb, stab, ctxT, ksum);
  qattn_kernel<<<dim3(64, 64), 256, 0, stream>>>(qb, projb, ctxT, ksum, attnb);

  // Wout + residual, LN1
  gemm_bt<1><<<gqkv, 256, 0, stream>>>(attnb, wob, nullptr, ybuf, b_out, src, RT, DD, DD);
  ln1_kernel<<<RT, 256, 0, stream>>>(ybuf, g1, be1, xb);

  // FFN
  gemm_bt<2><<<dim3(2048 / 128, RT / 128), 256, 0, stream>>>(xb, w1b, h1, nullptr, b1, nullptr, RT, 2048, DD);
  gemm_bt<3><<<dim3(DD / 128, RT / 128), 256, 0, stream>>>(h1, w2b, ff, nullptr, b2, nullptr, RT, DD, 2048);
  ln2_kernel<<<RT, 256, 0, stream>>>(xb, ff, g2, be2, (float*)d_out);
}

// Round 3
// 787.026 us; speedup vs baseline: 1.2881x; 1.1674x over previous
//
#include <hip/hip_runtime.h>

#define DEVI __device__ __forceinline__

using u16 = unsigned short;
using u32 = unsigned int;
using u64 = unsigned long long;

typedef __bf16 bf16x8 __attribute__((ext_vector_type(8)));
typedef float  f32x4  __attribute__((ext_vector_type(4)));

constexpr int BB = 4, NN = 4096, DD = 1024, HH = 16, DH = 64, MF = 256;
constexpr int RT = BB * NN;                       // 16384 rows total
constexpr int QKVS = 3072;                        // fused qkv row stride
constexpr float DN    = 0.35355339059327373f;     // 64^-0.25
constexpr float RATIO = 0.0625f;                  // 256^-0.5
constexpr float DIAGC = 0.0625f;                  // 0.5 * DN^2
constexpr float KEPSC = 1e-3f;

// ---------- scalar helpers ----------
DEVI u16 f2bf(float f) {
  u32 u = __float_as_uint(f);
  u32 r = u + 0x7fffu + ((u >> 16) & 1u);   // RNE
  return (u16)(r >> 16);
}
DEVI float bf2f(u16 u) { return __uint_as_float(((u32)u) << 16); }

// ---------- global_load_lds (CK addrspace pattern) ----------
typedef void __attribute__((address_space(1)))* gas1;
typedef void __attribute__((address_space(3)))* las3;
DEVI void gload_lds16(const void* g, void* l) {
  __builtin_amdgcn_global_load_lds((gas1)(u64)g, (las3)(u32)(u64)l, 16, 0, 0);
}

// swizzled fragment read from a [128][64]-bf16 LDS tile (row stride 128B)
DEVI bf16x8 ldswz(const u16* base, int row, int kbyte) {
  int p = (row << 7) + kbyte;
  p ^= (row & 7) << 4;                      // same involution as the staging side
  return *(const bf16x8*)((const char*)base + p);
}

// ============================================================
// casts
// ============================================================
__global__ void cast_kernel(const float* __restrict__ in, u16* __restrict__ out, int n4) {
  int i = blockIdx.x * 256 + threadIdx.x;
  int stride = gridDim.x * 256;
  for (; i < n4; i += stride) {
    float4 v = ((const float4*)in)[i];
    ushort4 o; o.x = f2bf(v.x); o.y = f2bf(v.y); o.z = f2bf(v.z); o.w = f2bf(v.w);
    ((ushort4*)out)[i] = o;
  }
}

__global__ void cast_proj_kernel(const float* __restrict__ in, u16* __restrict__ out) {
  int i = blockIdx.x * 256 + threadIdx.x;   // 4096 threads, 16384 elems
  float4 v = ((const float4*)in)[i];
  ushort4 o; o.x = f2bf(v.x * DN); o.y = f2bf(v.y * DN); o.z = f2bf(v.z * DN); o.w = f2bf(v.w * DN);
  ((ushort4*)out)[i] = o;
}

// ============================================================
// GEMM: C[i,j] = sum_k A[i,k] * B[j,k]   (both K-contiguous, bf16)
// 128x128 tile, BK=64, 4 waves (2x2), 16x16x32 MFMA, gload_lds + XOR swizzle
// EPI 0: C->bf16 | 2: +bias, gelu -> bf16 | 3: +bias -> bf16
// ============================================================
template <int EPI>
__global__ __launch_bounds__(256, 2) void gemm_bt(
    const u16* __restrict__ A, const u16* __restrict__ Bm,
    u16* __restrict__ Cb, const float* __restrict__ bias,
    int Ncols, int K)
{
  __shared__ __align__(16) u16 sA[128 * 64];
  __shared__ __align__(16) u16 sB[128 * 64];
  const int tid = threadIdx.x, lane = tid & 63;
  const int wv = tid >> 6, wr = wv >> 1, wc = wv & 1;
  const int bm = blockIdx.y, bn = blockIdx.x;

  f32x4 acc[4][4] = {};

  int rowS[4], colS[4], ldsb[4];
#pragma unroll
  for (int it = 0; it < 4; ++it) {
    int p = (it * 256 + tid) * 16;                // linear LDS byte this lane fills
    ldsb[it] = (it * 256 + (tid & ~63)) * 16;     // wave-uniform base
    int sp = p ^ (((p >> 7) & 7) << 4);           // inverse-swizzled source position
    rowS[it] = sp >> 7;
    colS[it] = (sp >> 1) & 63;
  }
  const size_t baseA = (size_t)bm * 128, baseB = (size_t)bn * 128;

  for (int kt = 0; kt < K; kt += 64) {
#pragma unroll
    for (int it = 0; it < 4; ++it)
      gload_lds16(A + (baseA + rowS[it]) * K + kt + colS[it], (char*)sA + ldsb[it]);
#pragma unroll
    for (int it = 0; it < 4; ++it)
      gload_lds16(Bm + (baseB + rowS[it]) * K + kt + colS[it], (char*)sB + ldsb[it]);
    __syncthreads();
#pragma unroll
    for (int kk = 0; kk < 2; ++kk) {
      const int kbyte = kk * 64 + ((lane >> 4) << 4);
      bf16x8 a[4], b[4];
#pragma unroll
      for (int i = 0; i < 4; ++i) a[i] = ldswz(sA, wr * 64 + i * 16 + (lane & 15), kbyte);
#pragma unroll
      for (int i = 0; i < 4; ++i) b[i] = ldswz(sB, wc * 64 + i * 16 + (lane & 15), kbyte);
#pragma unroll
      for (int i = 0; i < 4; ++i)
#pragma unroll
        for (int j = 0; j < 4; ++j)
          acc[i][j] = __builtin_amdgcn_mfma_f32_16x16x32_bf16(a[i], b[j], acc[i][j], 0, 0, 0);
    }
    __syncthreads();
  }

#pragma unroll
  for (int i = 0; i < 4; ++i) {
    const int gr0 = bm * 128 + wr * 64 + i * 16 + ((lane >> 4) << 2);
#pragma unroll
    for (int j = 0; j < 4; ++j) {
      const int gc = bn * 128 + wc * 64 + j * 16 + (lane & 15);
#pragma unroll
      for (int r = 0; r < 4; ++r) {
        const size_t o = (size_t)(gr0 + r) * Ncols + gc;
        const float v = acc[i][j][r];
        if constexpr (EPI == 0) {
          Cb[o] = f2bf(v);
        } else if constexpr (EPI == 2) {
          float t = v + bias[gc];
          Cb[o] = f2bf(0.5f * t * (1.0f + erff(t * 0.70710678118654752f)));
        } else {
          Cb[o] = f2bf(v + bias[gc]);
        }
      }
    }
  }
}

// ============================================================
// key pass 1: per-block max of data_dash -> pmax[block]
// ============================================================
__global__ __launch_bounds__(256) void kmax_kernel(
    const u16* __restrict__ qkvb, const u16* __restrict__ projb, float* __restrict__ pmax)
{
  __shared__ __align__(16) u16 sX[64 * 72];
  __shared__ float sred[4];
  const int tid = threadIdx.x, lane = tid & 63, wv = tid >> 6;
  const int bh = blockIdx.x, b = bh >> 4, h = bh & 15;
  const int n0 = blockIdx.y * 64;

  for (int i = tid; i < 512; i += 256) {
    int r = i >> 3, c8 = (i & 7) << 3;
    uint4 v = *(const uint4*)(qkvb + ((size_t)(b * NN + n0 + r)) * QKVS + 1024 + h * DH + c8);
    *(uint4*)&sX[r * 72 + c8] = v;
  }
  __syncthreads();

  f32x4 dacc[16] = {};
#pragma unroll
  for (int kk = 0; kk < 2; ++kk) {
    const int ko = kk * 32 + ((lane >> 4) << 3);
    bf16x8 a = *(const bf16x8*)&sX[(wv * 16 + (lane & 15)) * 72 + ko];
#pragma unroll
    for (int f = 0; f < 16; ++f) {
      bf16x8 bb = *(const bf16x8*)(projb + (f * 16 + (lane & 15)) * 64 + ko);
      dacc[f] = __builtin_amdgcn_mfma_f32_16x16x32_bf16(a, bb, dacc[f], 0, 0, 0);
    }
  }
  float mx = -1e30f;
#pragma unroll
  for (int f = 0; f < 16; ++f)
#pragma unroll
    for (int r = 0; r < 4; ++r) mx = fmaxf(mx, dacc[f][r]);
#pragma unroll
  for (int m = 1; m < 64; m <<= 1) mx = fmaxf(mx, __shfl_xor(mx, m));
  if (lane == 0) sred[wv] = mx;
  __syncthreads();
  if (tid == 0)
    pmax[blockIdx.y * gridDim.x + blockIdx.x] =
        fmaxf(fmaxf(sred[0], sred[1]), fmaxf(sred[2], sred[3]));
}

// second stage: 4096 partial maxes -> stab[0]
__global__ __launch_bounds__(256) void reduce_max_kernel(
    const float* __restrict__ pmax, float* __restrict__ stab)
{
  const int tid = threadIdx.x;
  float mx = -1e30f;
#pragma unroll
  for (int i = 0; i < 16; ++i) mx = fmaxf(mx, pmax[i * 256 + tid]);
#pragma unroll
  for (int m = 1; m < 64; m <<= 1) mx = fmaxf(mx, __shfl_xor(mx, m));
  __shared__ float sred[4];
  if ((tid & 63) == 0) sred[tid >> 6] = mx;
  __syncthreads();
  if (tid == 0)
    stab[0] = fmaxf(fmaxf(sred[0], sred[1]), fmaxf(sred[2], sred[3]));
}

// ============================================================
// key pass 2: kp -> partial ksum, partial ctx (plain stores, no atomics)
// ctxP[slice][bh][64 j][256 m], ksumP2[slice][bh][wave][256]
// ============================================================
__global__ __launch_bounds__(256, 1) void kctx_kernel(
    const u16* __restrict__ qkvb, const u16* __restrict__ projb,
    const float* __restrict__ stab_p,
    float* __restrict__ ctxP, float* __restrict__ ksumP2)
{
  __shared__ __align__(16) u16 sX[64 * 72];
  __shared__ __align__(16) u16 sVT[64 * 72];
  __shared__ __align__(16) u16 sKpT[256 * 72];
  __shared__ float sDiag[64];
  const int tid = threadIdx.x, lane = tid & 63, wv = tid >> 6;
  const int bh = blockIdx.x, b = bh >> 4, h = bh & 15;
  const int sl = blockIdx.y;
  const float stab = stab_p[0];

  f32x4 cacc[16] = {};
  float ksacc[16] = {};
  const int row_base = wv * 16 + ((lane >> 4) << 2);

  for (int t = 0; t < 8; ++t) {
    const int n0 = sl * 512 + t * 64;
    if (t) __syncthreads();
    for (int i = tid; i < 512; i += 256) {
      int r = i >> 3, c8 = (i & 7) << 3;
      size_t g = ((size_t)(b * NN + n0 + r)) * QKVS + h * DH + c8;
      uint4 xv = *(const uint4*)(qkvb + g + 1024);   // k
      *(uint4*)&sX[r * 72 + c8] = xv;
      uint4 vv = *(const uint4*)(qkvb + g + 2048);   // v
      const u16* pv = (const u16*)&vv;
#pragma unroll
      for (int j = 0; j < 8; ++j) sVT[(c8 + j) * 72 + r] = pv[j];
    }
    __syncthreads();
    {  // diag = 0.5*dn^2*sum x^2 per row
      int r = tid >> 2, qq = tid & 3;
      float s = 0;
#pragma unroll
      for (int j = 0; j < 16; ++j) { float x = bf2f(sX[r * 72 + qq * 16 + j]); s += x * x; }
      s += __shfl_xor(s, 1); s += __shfl_xor(s, 2);
      if (qq == 0) sDiag[r] = DIAGC * s;
    }
    f32x4 dacc[16] = {};
#pragma unroll
    for (int kk = 0; kk < 2; ++kk) {
      const int ko = kk * 32 + ((lane >> 4) << 3);
      bf16x8 a = *(const bf16x8*)&sX[(wv * 16 + (lane & 15)) * 72 + ko];
#pragma unroll
      for (int f = 0; f < 16; ++f) {
        bf16x8 bb = *(const bf16x8*)(projb + (f * 16 + (lane & 15)) * 64 + ko);
        dacc[f] = __builtin_amdgcn_mfma_f32_16x16x32_bf16(a, bb, dacc[f], 0, 0, 0);
      }
    }
    __syncthreads();   // sDiag ready
#pragma unroll
    for (int f = 0; f < 16; ++f) {
      float kvv[4]; float cs = 0;
#pragma unroll
      for (int r = 0; r < 4; ++r) {
        float val = RATIO * (__expf(dacc[f][r] - sDiag[row_base + r] - stab) + KEPSC);
        kvv[r] = val; cs += val;
      }
      cs += __shfl_xor(cs, 16); cs += __shfl_xor(cs, 32);
      ksacc[f] += cs;
      ushort4 pk; pk.x = f2bf(kvv[0]); pk.y = f2bf(kvv[1]); pk.z = f2bf(kvv[2]); pk.w = f2bf(kvv[3]);
      *(ushort4*)&sKpT[(f * 16 + (lane & 15)) * 72 + row_base] = pk;
    }
    __syncthreads();
#pragma unroll
    for (int kk = 0; kk < 2; ++kk) {
      const int ko = kk * 32 + ((lane >> 4) << 3);
      bf16x8 a = *(const bf16x8*)&sVT[(wv * 16 + (lane & 15)) * 72 + ko];
#pragma unroll
      for (int f = 0; f < 16; ++f) {
        bf16x8 bb = *(const bf16x8*)&sKpT[(f * 16 + (lane & 15)) * 72 + ko];
        cacc[f] = __builtin_amdgcn_mfma_f32_16x16x32_bf16(a, bb, cacc[f], 0, 0, 0);
      }
    }
  }
  // plain partial stores (full overwrite — no init needed)
  float* cp = ctxP + (size_t)(sl * 64 + bh) * 16384;
#pragma unroll
  for (int f = 0; f < 16; ++f) {
    const int m = f * 16 + (lane & 15);
#pragma unroll
    for (int r = 0; r < 4; ++r)
      cp[(row_base + r) * 256 + m] = cacc[f][r];
  }
  if (lane < 16) {
    float* kp = ksumP2 + (size_t)((sl * 64 + bh) * 4 + wv) * 256;
#pragma unroll
    for (int f = 0; f < 16; ++f) kp[f * 16 + lane] = ksacc[f];
  }
}

// ============================================================
// finalize: sum partials -> ctxb (bf16, linear) + ksum (f32)
// ============================================================
__global__ __launch_bounds__(256) void ctxfin_kernel(
    const float* __restrict__ ctxP, const float* __restrict__ ksumP2,
    u16* __restrict__ ctxb, float* __restrict__ ksum)
{
  const int bid = blockIdx.x, tid = threadIdx.x;
  if (bid < 1024) {
    const int idx = bid * 256 + tid;          // [0, 262144)
    const int bh = idx >> 12, pos = idx & 4095;
    float4 s = {0, 0, 0, 0};
#pragma unroll
    for (int sl = 0; sl < 8; ++sl) {
      float4 v = *(const float4*)(ctxP + (size_t)(sl * 64 + bh) * 16384 + pos * 4);
      s.x += v.x; s.y += v.y; s.z += v.z; s.w += v.w;
    }
    ushort4 o; o.x = f2bf(s.x); o.y = f2bf(s.y); o.z = f2bf(s.z); o.w = f2bf(s.w);
    *(ushort4*)(ctxb + (size_t)bh * 16384 + pos * 4) = o;
  } else {
    const int idx = (bid - 1024) * 256 + tid; // [0, 16384)
    const int bh = idx >> 8, m = idx & 255;
    float s = 0;
#pragma unroll
    for (int sl = 0; sl < 8; ++sl)
#pragma unroll
      for (int w = 0; w < 4; ++w)
        s += ksumP2[(size_t)((sl * 64 + bh) * 4 + w) * 256 + m];
    ksum[idx] = s;
  }
}

// ============================================================
// query pass: qp features + d_inv + attn = (qp @ ctx) * d_inv
// 2 row-tiles per block; ctx staged once via gload_lds w/ XOR-swizzled source
// ============================================================
__global__ __launch_bounds__(256, 2) void qattn_kernel(
    const u16* __restrict__ qkvb, const u16* __restrict__ projb,
    const u16* __restrict__ ctxb, const float* __restrict__ ksum,
    u16* __restrict__ attnb)
{
  __shared__ __align__(16) u16 sCtx[64 * 256];   // 32KB, swizzled content
  __shared__ __align__(16) u16 sX[64 * 72];
  __shared__ __align__(16) u16 sQp[64 * 264];
  __shared__ float sKsum[256];
  __shared__ float sDiag[64];
  __shared__ float sDinv[64];
  const int tid = threadIdx.x, lane = tid & 63, wv = tid >> 6;
  const int bh = blockIdx.x, b = bh >> 4, h = bh & 15;

  {  // stage ctx (32 KB): LDS linear, global source inverse-swizzled per-lane
    const char* cbase = (const char*)(ctxb + (size_t)bh * 16384);
#pragma unroll
    for (int it = 0; it < 8; ++it) {
      int p = (it * 256 + tid) * 16;
      int ldsb = (it * 256 + (tid & ~63)) * 16;
      int q = p ^ (((p >> 9) & 7) << 4);
      gload_lds16(cbase + q, (char*)sCtx + ldsb);
    }
  }
  sKsum[tid] = ksum[bh * 256 + tid];

  const int row_base = wv * 16 + ((lane >> 4) << 2);
  const int wr = wv >> 1, wc = wv & 1;

  for (int rt = 0; rt < 2; ++rt) {
    const int n0 = (blockIdx.y * 2 + rt) * 64;
    for (int i = tid; i < 512; i += 256) {
      int r = i >> 3, c8 = (i & 7) << 3;
      uint4 v = *(const uint4*)(qkvb + ((size_t)(b * NN + n0 + r)) * QKVS + h * DH + c8);
      *(uint4*)&sX[r * 72 + c8] = v;
    }
    __syncthreads();
    {
      int r = tid >> 2, qq = tid & 3;
      float s = 0;
#pragma unroll
      for (int j = 0; j < 16; ++j) { float x = bf2f(sX[r * 72 + qq * 16 + j]); s += x * x; }
      s += __shfl_xor(s, 1); s += __shfl_xor(s, 2);
      if (qq == 0) sDiag[r] = DIAGC * s;
    }
    f32x4 dacc[16] = {};
#pragma unroll
    for (int kk = 0; kk < 2; ++kk) {
      const int ko = kk * 32 + ((lane >> 4) << 3);
      bf16x8 a = *(const bf16x8*)&sX[(wv * 16 + (lane & 15)) * 72 + ko];
#pragma unroll
      for (int f = 0; f < 16; ++f) {
        bf16x8 bb = *(const bf16x8*)(projb + (f * 16 + (lane & 15)) * 64 + ko);
        dacc[f] = __builtin_amdgcn_mfma_f32_16x16x32_bf16(a, bb, dacc[f], 0, 0, 0);
      }
    }
    __syncthreads();   // sDiag ready
#pragma unroll
    for (int r = 0; r < 4; ++r) {
      const int row = row_base + r;
      float mx = dacc[0][r];
#pragma unroll
      for (int f = 1; f < 16; ++f) mx = fmaxf(mx, dacc[f][r]);
      mx = fmaxf(mx, __shfl_xor(mx, 1));
      mx = fmaxf(mx, __shfl_xor(mx, 2));
      mx = fmaxf(mx, __shfl_xor(mx, 4));
      mx = fmaxf(mx, __shfl_xor(mx, 8));
      const float dg = sDiag[row];
      float ds = 0;
#pragma unroll
      for (int f = 0; f < 16; ++f) {
        float qv = RATIO * (__expf(dacc[f][r] - dg - mx) + KEPSC);
        dacc[f][r] = qv;
        ds += qv * sKsum[f * 16 + (lane & 15)];
      }
      ds += __shfl_xor(ds, 1); ds += __shfl_xor(ds, 2);
      ds += __shfl_xor(ds, 4); ds += __shfl_xor(ds, 8);
      if ((lane & 15) == 0) sDinv[row] = 1.0f / ds;
    }
#pragma unroll
    for (int f = 0; f < 16; ++f)
#pragma unroll
      for (int r = 0; r < 4; ++r)
        sQp[(row_base + r) * 264 + f * 16 + (lane & 15)] = f2bf(dacc[f][r]);
    __syncthreads();

    f32x4 acc2[2][2] = {};
#pragma unroll
    for (int kk = 0; kk < 8; ++kk) {
      const int koe = kk * 32 + ((lane >> 4) << 3);          // element offset
      const int kob = koe * 2;                                // byte offset
      bf16x8 a0 = *(const bf16x8*)&sQp[(wr * 32 + (lane & 15)) * 264 + koe];
      bf16x8 a1 = *(const bf16x8*)&sQp[(wr * 32 + 16 + (lane & 15)) * 264 + koe];
      const int j0 = wc * 32 + (lane & 15), j1 = j0 + 16;
      bf16x8 b0 = *(const bf16x8*)((const char*)sCtx + (((j0 << 9) + kob) ^ ((j0 & 7) << 4)));
      bf16x8 b1 = *(const bf16x8*)((const char*)sCtx + (((j1 << 9) + kob) ^ ((j1 & 7) << 4)));
      acc2[0][0] = __builtin_amdgcn_mfma_f32_16x16x32_bf16(a0, b0, acc2[0][0], 0, 0, 0);
      acc2[0][1] = __builtin_amdgcn_mfma_f32_16x16x32_bf16(a0, b1, acc2[0][1], 0, 0, 0);
      acc2[1][0] = __builtin_amdgcn_mfma_f32_16x16x32_bf16(a1, b0, acc2[1][0], 0, 0, 0);
      acc2[1][1] = __builtin_amdgcn_mfma_f32_16x16x32_bf16(a1, b1, acc2[1][1], 0, 0, 0);
    }
#pragma unroll
    for (int mi = 0; mi < 2; ++mi)
#pragma unroll
      for (int ni = 0; ni < 2; ++ni)
#pragma unroll
        for (int r = 0; r < 4; ++r) {
          const int row = wr * 32 + mi * 16 + ((lane >> 4) << 2) + r;
          const int col = wc * 32 + ni * 16 + (lane & 15);
          float v = acc2[mi][ni][r] * sDinv[row];
          attnb[((size_t)(b * NN + n0 + row)) * DD + h * DH + col] = f2bf(v);
        }
    __syncthreads();   // protect sQp/sDinv before next rt overwrite
  }
}

// ============================================================
// LayerNorms
// ============================================================
__global__ __launch_bounds__(256) void ln1_kernel(
    const float* __restrict__ src, const u16* __restrict__ wout,
    const float* __restrict__ g, const float* __restrict__ be, u16* __restrict__ xb)
{
  const int row = blockIdx.x, tid = threadIdx.x;
  const float4 sv = ((const float4*)(src + (size_t)row * DD))[tid];
  const ushort4 wv = ((const ushort4*)(wout + (size_t)row * DD))[tid];
  float x0 = sv.x + bf2f(wv.x);
  float x1 = sv.y + bf2f(wv.y);
  float x2 = sv.z + bf2f(wv.z);
  float x3 = sv.w + bf2f(wv.w);
  float s = x0 + x1 + x2 + x3;
  float ss = x0 * x0 + x1 * x1 + x2 * x2 + x3 * x3;
#pragma unroll
  for (int m = 1; m < 64; m <<= 1) { s += __shfl_xor(s, m); ss += __shfl_xor(ss, m); }
  __shared__ float red[8];
  if ((tid & 63) == 0) { red[tid >> 6] = s; red[4 + (tid >> 6)] = ss; }
  __syncthreads();
  s = red[0] + red[1] + red[2] + red[3];
  ss = red[4] + red[5] + red[6] + red[7];
  const float mu = s * (1.0f / DD);
  const float rs = rsqrtf(ss * (1.0f / DD) - mu * mu + 1e-5f);
  const float4 gv = ((const float4*)g)[tid];
  const float4 bv = ((const float4*)be)[tid];
  ushort4 o;
  o.x = f2bf((x0 - mu) * rs * gv.x + bv.x);
  o.y = f2bf((x1 - mu) * rs * gv.y + bv.y);
  o.z = f2bf((x2 - mu) * rs * gv.z + bv.z);
  o.w = f2bf((x3 - mu) * rs * gv.w + bv.w);
  ((ushort4*)(xb + (size_t)row * DD))[tid] = o;
}

__global__ __launch_bounds__(256) void ln2_kernel(
    const u16* __restrict__ xb, const u16* __restrict__ ff,
    const float* __restrict__ g, const float* __restrict__ be, float* __restrict__ out)
{
  const int row = blockIdx.x, tid = threadIdx.x;
  const ushort4 xv = ((const ushort4*)(xb + (size_t)row * DD))[tid];
  const ushort4 fv = ((const ushort4*)(ff + (size_t)row * DD))[tid];
  float x0 = bf2f(xv.x) + bf2f(fv.x);
  float x1 = bf2f(xv.y) + bf2f(fv.y);
  float x2 = bf2f(xv.z) + bf2f(fv.z);
  float x3 = bf2f(xv.w) + bf2f(fv.w);
  float s = x0 + x1 + x2 + x3;
  float ss = x0 * x0 + x1 * x1 + x2 * x2 + x3 * x3;
#pragma unroll
  for (int m = 1; m < 64; m <<= 1) { s += __shfl_xor(s, m); ss += __shfl_xor(ss, m); }
  __shared__ float red[8];
  if ((tid & 63) == 0) { red[tid >> 6] = s; red[4 + (tid >> 6)] = ss; }
  __syncthreads();
  s = red[0] + red[1] + red[2] + red[3];
  ss = red[4] + red[5] + red[6] + red[7];
  const float mu = s * (1.0f / DD);
  const float rs = rsqrtf(ss * (1.0f / DD) - mu * mu + 1e-5f);
  const float4 gv = ((const float4*)g)[tid];
  const float4 bv = ((const float4*)be)[tid];
  float4 o;
  o.x = (x0 - mu) * rs * gv.x + bv.x;
  o.y = (x1 - mu) * rs * gv.y + bv.y;
  o.z = (x2 - mu) * rs * gv.z + bv.z;
  o.w = (x3 - mu) * rs * gv.w + bv.w;
  ((float4*)(out + (size_t)row * DD))[tid] = o;
}

// ============================================================
// launch
// ============================================================
extern "C" void kernel_launch(void* const* d_in, const int* in_sizes, int n_in,
                              void* d_out, int out_size, void* d_ws, size_t ws_size,
                              hipStream_t stream) {
  (void)in_sizes; (void)n_in; (void)out_size; (void)ws_size;
  const float* src   = (const float*)d_in[0];
  const float* Wq    = (const float*)d_in[1];
  const float* Wk    = (const float*)d_in[2];
  const float* Wv    = (const float*)d_in[3];
  const float* Wout  = (const float*)d_in[4];
  const float* b_out = (const float*)d_in[5];
  const float* proj  = (const float*)d_in[6];
  const float* g1    = (const float*)d_in[7];
  const float* be1   = (const float*)d_in[8];
  const float* W1    = (const float*)d_in[9];
  const float* b1    = (const float*)d_in[10];
  const float* W2    = (const float*)d_in[11];
  const float* b2    = (const float*)d_in[12];
  const float* g2    = (const float*)d_in[13];
  const float* be2   = (const float*)d_in[14];

  char* ws = (char*)d_ws;
  // layout (bytes):
  //  [0, 33.55M)      srcb bf16 -> ctxP f32 (32M) -> attnb bf16 -> h1 head
  //  [33.55M, 134.2M) qkvb bf16 [16384][3072]; later: h1 tail (to 67.1M),
  //                   woutb/ff bf16 at [100.66M, 134.2M)
  //  [134.2M, 151.0M) weights: wqkv(3x2M), wob, w1b, w2b, projb
  //  [151.0M, ~155.3M) ctxb(2M) ksum(64K) ksumP2(2M) pmax(16K) stab
  constexpr size_t OFF_SRCB = 0;
  constexpr size_t OFF_QKV  = 33554432;
  constexpr size_t OFF_WOUTB= 100663296;
  constexpr size_t OFF_WQ   = 134217728;
  constexpr size_t OFF_WO   = 140509184;
  constexpr size_t OFF_W1   = 142606336;
  constexpr size_t OFF_W2   = 146800640;
  constexpr size_t OFF_PROJ = 150994944;
  constexpr size_t OFF_CTXB = 151027712;
  constexpr size_t OFF_KSUM = 153124864;
  constexpr size_t OFF_KSP2 = 153190400;
  constexpr size_t OFF_PMAX = 155287552;
  constexpr size_t OFF_STAB = 155303936;

  u16* srcb  = (u16*)(ws + OFF_SRCB);
  u16* qkvb  = (u16*)(ws + OFF_QKV);
  u16* wqkvb = (u16*)(ws + OFF_WQ);        // [3072][1024] (Wq|Wk|Wv rows)
  u16* wob   = (u16*)(ws + OFF_WO);
  u16* w1b   = (u16*)(ws + OFF_W1);
  u16* w2b   = (u16*)(ws + OFF_W2);
  u16* projb = (u16*)(ws + OFF_PROJ);
  u16* ctxb  = (u16*)(ws + OFF_CTXB);
  float* ksum  = (float*)(ws + OFF_KSUM);
  float* ksumP2= (float*)(ws + OFF_KSP2);
  float* pmax  = (float*)(ws + OFF_PMAX);
  float* stab  = (float*)(ws + OFF_STAB);
  float* ctxP  = (float*)(ws + OFF_SRCB);  // alias srcb (dead after QKV gemm)
  u16* attnb = (u16*)(ws + OFF_SRCB);      // alias ctxP (dead after ctxfin)
  u16* woutb = (u16*)(ws + OFF_WOUTB);     // alias qkv rows (dead after qattn)
  u16* xb    = (u16*)(ws + OFF_QKV + 33554432);  // middle third (dead after kctx/qattn)
  u16* h1    = (u16*)(ws + OFF_SRCB);      // [0, 67.1M)
  u16* ff    = (u16*)(ws + OFF_WOUTB);     // woutb slot (dead after ln1)

  // casts
  cast_kernel<<<4096, 256, 0, stream>>>(src, srcb, RT * DD / 4);
  cast_kernel<<<1024, 256, 0, stream>>>(Wq, wqkvb, DD * DD / 4);
  cast_kernel<<<1024, 256, 0, stream>>>(Wk, wqkvb + DD * DD, DD * DD / 4);
  cast_kernel<<<1024, 256, 0, stream>>>(Wv, wqkvb + 2 * DD * DD, DD * DD / 4);
  cast_kernel<<<1024, 256, 0, stream>>>(Wout, wob, DD * DD / 4);
  cast_kernel<<<2048, 256, 0, stream>>>(W1, w1b, 2048 * DD / 4);
  cast_kernel<<<2048, 256, 0, stream>>>(W2, w2b, 2048 * DD / 4);
  cast_proj_kernel<<<16, 256, 0, stream>>>(proj, projb);

  // fused QKV projection: [16384][3072]
  gemm_bt<0><<<dim3(QKVS / 128, RT / 128), 256, 0, stream>>>(srcb, wqkvb, qkvb, nullptr, QKVS, DD);

  // performer features
  kmax_kernel<<<dim3(64, 64), 256, 0, stream>>>(qkvb, projb, pmax);
  reduce_max_kernel<<<1, 256, 0, stream>>>(pmax, stab);
  kctx_kernel<<<dim3(64, 8), 256, 0, stream>>>(qkvb, projb, stab, ctxP, ksumP2);
  ctxfin_kernel<<<1088, 256, 0, stream>>>(ctxP, ksumP2, ctxb, ksum);
  qattn_kernel<<<dim3(64, 32), 256, 0, stream>>>(qkvb, projb, ctxb, ksum, attnb);

  // Wout (+bias) -> bf16; residual folded into ln1
  gemm_bt<3><<<dim3(DD / 128, RT / 128), 256, 0, stream>>>(attnb, wob, woutb, b_out, DD, DD);
  ln1_kernel<<<RT, 256, 0, stream>>>(src, woutb, g1, be1, xb);

  // FFN
  gemm_bt<2><<<dim3(2048 / 128, RT / 128), 256, 0, stream>>>(xb, w1b, h1, b1, 2048, DD);
  gemm_bt<3><<<dim3(DD / 128, RT / 128), 256, 0, stream>>>(h1, w2b, ff, b2, DD, 2048);
  ln2_kernel<<<RT, 256, 0, stream>>>(xb, ff, g2, be2, (float*)d_out);
}

// Round 5
// 721.288 us; speedup vs baseline: 1.4055x; 1.0911x over previous
//
#include <hip/hip_runtime.h>

#define DEVI __device__ __forceinline__

using u16 = unsigned short;
using u32 = unsigned int;
using u64 = unsigned long long;

typedef __bf16 bf16x8 __attribute__((ext_vector_type(8)));
typedef float  f32x4  __attribute__((ext_vector_type(4)));

constexpr int BB = 4, NN = 4096, DD = 1024, HH = 16, DH = 64, MF = 256;
constexpr int RT = BB * NN;                       // 16384 rows total
constexpr int QKVS = 3072;                        // fused qkv row stride
constexpr float DN    = 0.35355339059327373f;     // 64^-0.25
constexpr float RATIO = 0.0625f;                  // 256^-0.5
constexpr float DIAGC = 0.0625f;                  // 0.5 * DN^2
constexpr float KEPSC = 1e-3f;

// ---------- scalar helpers ----------
DEVI u16 f2bf(float f) {
  u32 u = __float_as_uint(f);
  u32 r = u + 0x7fffu + ((u >> 16) & 1u);   // RNE
  return (u16)(r >> 16);
}
DEVI float bf2f(u16 u) { return __uint_as_float(((u32)u) << 16); }

// ---------- global_load_lds (CK addrspace pattern) ----------
typedef void __attribute__((address_space(1)))* gas1;
typedef void __attribute__((address_space(3)))* las3;
DEVI void gload_lds16(const void* g, void* l) {
  __builtin_amdgcn_global_load_lds((gas1)(u64)g, (las3)(u32)(u64)l, 16, 0, 0);
}

// swizzled fragment read from a [rows][64]-bf16 LDS tile (row stride 128B)
DEVI bf16x8 ldswz(const u16* base, int row, int kbyte) {
  int p = (row << 7) + kbyte;
  p ^= (row & 7) << 4;                      // same involution as the staging side
  return *(const bf16x8*)((const char*)base + p);
}

// ============================================================
// casts
// ============================================================
__global__ void cast_kernel(const float* __restrict__ in, u16* __restrict__ out, int n4) {
  int i = blockIdx.x * 256 + threadIdx.x;
  int stride = gridDim.x * 256;
  for (; i < n4; i += stride) {
    float4 v = ((const float4*)in)[i];
    ushort4 o; o.x = f2bf(v.x); o.y = f2bf(v.y); o.z = f2bf(v.z); o.w = f2bf(v.w);
    ((ushort4*)out)[i] = o;
  }
}

// all weights in one launch: wq|wk|wv -> wqkvb, wo -> wob, w1, w2, proj(*DN)
__global__ void cast_weights_kernel(
    const float* __restrict__ Wq, const float* __restrict__ Wk,
    const float* __restrict__ Wv, const float* __restrict__ Wout,
    const float* __restrict__ W1, const float* __restrict__ W2,
    const float* __restrict__ proj,
    u16* __restrict__ wqkvb, u16* __restrict__ wob,
    u16* __restrict__ w1b, u16* __restrict__ w2b, u16* __restrict__ projb)
{
  constexpr int TOT = 2101248;   // f4 count: 4*262144 + 2*524288 + 4096
  int i = blockIdx.x * 256 + threadIdx.x;
  const int stride = gridDim.x * 256;
  for (; i < TOT; i += stride) {
    const float* s; u16* d; int loc; float sc = 1.0f;
    if (i < 1048576) {
      int seg = i >> 18; loc = i & 262143;
      s = (seg == 0) ? Wq : (seg == 1) ? Wk : (seg == 2) ? Wv : Wout;
      d = (seg < 3) ? (wqkvb + seg * 1048576) : wob;
    } else if (i < 1572864) { loc = i - 1048576; s = W1; d = w1b; }
    else if (i < 2097152)   { loc = i - 1572864; s = W2; d = w2b; }
    else                    { loc = i - 2097152; s = proj; d = projb; sc = DN; }
    float4 v = ((const float4*)s)[loc];
    ushort4 o; o.x = f2bf(v.x * sc); o.y = f2bf(v.y * sc); o.z = f2bf(v.z * sc); o.w = f2bf(v.w * sc);
    ((ushort4*)d)[loc] = o;
  }
}

// ============================================================
// GEMM: C[i,j] = sum_k A[i,k] * B[j,k]   (both K-contiguous, bf16)
// 256x128 tile, BK=64, 8 waves (4x2), 512 thr, 16x16x32 MFMA,
// gload_lds + XOR swizzle + XCD-aware block swizzle.
// EPI 0: C->bf16 | 2: +bias, gelu -> bf16 | 3: +bias -> bf16
// ============================================================
template <int EPI>
__global__ __launch_bounds__(512, 4) void gemm_bt(
    const u16* __restrict__ A, int lda, const u16* __restrict__ Bm,
    u16* __restrict__ Cb, const float* __restrict__ bias,
    int Ncols, int K)
{
  __shared__ __align__(16) u16 sA[256 * 64];   // 32 KB
  __shared__ __align__(16) u16 sB[128 * 64];   // 16 KB
  const int tid = threadIdx.x, lane = tid & 63;
  const int wv = tid >> 6, wr = wv >> 1, wc = wv & 1;

  // XCD-aware bijective swizzle (all grids here have nwg % 8 == 0)
  const int gx = gridDim.x;
  const int wg = blockIdx.y * gx + blockIdx.x;
  const int cpx = (gx * gridDim.y) >> 3;
  const int swz = (wg & 7) * cpx + (wg >> 3);
  const int bn = swz % gx, bm = swz / gx;

  f32x4 acc[4][4] = {};

  int rowS[4], colS[4], ldsb[4];
#pragma unroll
  for (int it = 0; it < 4; ++it) {
    int p = (it * 512 + tid) * 16;                // linear LDS byte this lane fills
    ldsb[it] = (it * 512 + (tid & ~63)) * 16;     // wave-uniform base
    int sp = p ^ (((p >> 7) & 7) << 4);           // inverse-swizzled source position
    rowS[it] = sp >> 7;
    colS[it] = (sp >> 1) & 63;
  }
  const size_t baseA = (size_t)bm * 256, baseB = (size_t)bn * 128;

  for (int kt = 0; kt < K; kt += 64) {
#pragma unroll
    for (int it = 0; it < 4; ++it)
      gload_lds16(A + (baseA + rowS[it]) * lda + kt + colS[it], (char*)sA + ldsb[it]);
#pragma unroll
    for (int it = 0; it < 2; ++it)
      gload_lds16(Bm + (baseB + rowS[it]) * K + kt + colS[it], (char*)sB + ldsb[it]);
    __syncthreads();
#pragma unroll
    for (int kk = 0; kk < 2; ++kk) {
      const int kbyte = kk * 64 + ((lane >> 4) << 4);
      bf16x8 a[4], b[4];
#pragma unroll
      for (int i = 0; i < 4; ++i) a[i] = ldswz(sA, wr * 64 + i * 16 + (lane & 15), kbyte);
#pragma unroll
      for (int i = 0; i < 4; ++i) b[i] = ldswz(sB, wc * 64 + i * 16 + (lane & 15), kbyte);
#pragma unroll
      for (int i = 0; i < 4; ++i)
#pragma unroll
        for (int j = 0; j < 4; ++j)
          acc[i][j] = __builtin_amdgcn_mfma_f32_16x16x32_bf16(a[i], b[j], acc[i][j], 0, 0, 0);
    }
    __syncthreads();
  }

#pragma unroll
  for (int i = 0; i < 4; ++i) {
    const int gr0 = bm * 256 + wr * 64 + i * 16 + ((lane >> 4) << 2);
#pragma unroll
    for (int j = 0; j < 4; ++j) {
      const int gc = bn * 128 + wc * 64 + j * 16 + (lane & 15);
#pragma unroll
      for (int r = 0; r < 4; ++r) {
        const size_t o = (size_t)(gr0 + r) * Ncols + gc;
        const float v = acc[i][j][r];
        if constexpr (EPI == 0) {
          Cb[o] = f2bf(v);
        } else if constexpr (EPI == 2) {
          float t = v + bias[gc];
          Cb[o] = f2bf(0.5f * t * (1.0f + erff(t * 0.70710678118654752f)));
        } else {
          Cb[o] = f2bf(v + bias[gc]);
        }
      }
    }
  }
}

// ============================================================
// key pass 1: per-block max of data_dash -> pmax[block]
// ============================================================
__global__ __launch_bounds__(256) void kmax_kernel(
    const u16* __restrict__ qkvb, const u16* __restrict__ projb, float* __restrict__ pmax)
{
  __shared__ __align__(16) u16 sX[64 * 72];
  __shared__ float sred[4];
  const int tid = threadIdx.x, lane = tid & 63, wv = tid >> 6;
  const int bh = blockIdx.x, b = bh >> 4, h = bh & 15;
  const int n0 = blockIdx.y * 64;

  for (int i = tid; i < 512; i += 256) {
    int r = i >> 3, c8 = (i & 7) << 3;
    uint4 v = *(const uint4*)(qkvb + ((size_t)(b * NN + n0 + r)) * QKVS + 1024 + h * DH + c8);
    *(uint4*)&sX[r * 72 + c8] = v;
  }
  __syncthreads();

  f32x4 dacc[16] = {};
#pragma unroll
  for (int kk = 0; kk < 2; ++kk) {
    const int ko = kk * 32 + ((lane >> 4) << 3);
    bf16x8 a = *(const bf16x8*)&sX[(wv * 16 + (lane & 15)) * 72 + ko];
#pragma unroll
    for (int f = 0; f < 16; ++f) {
      bf16x8 bb = *(const bf16x8*)(projb + (f * 16 + (lane & 15)) * 64 + ko);
      dacc[f] = __builtin_amdgcn_mfma_f32_16x16x32_bf16(a, bb, dacc[f], 0, 0, 0);
    }
  }
  float mx = -1e30f;
#pragma unroll
  for (int f = 0; f < 16; ++f)
#pragma unroll
    for (int r = 0; r < 4; ++r) mx = fmaxf(mx, dacc[f][r]);
#pragma unroll
  for (int m = 1; m < 64; m <<= 1) mx = fmaxf(mx, __shfl_xor(mx, m));
  if (lane == 0) sred[wv] = mx;
  __syncthreads();
  if (tid == 0)
    pmax[blockIdx.y * gridDim.x + blockIdx.x] =
        fmaxf(fmaxf(sred[0], sred[1]), fmaxf(sred[2], sred[3]));
}

// second stage: 4096 partial maxes -> stab[0]
__global__ __launch_bounds__(256) void reduce_max_kernel(
    const float* __restrict__ pmax, float* __restrict__ stab)
{
  const int tid = threadIdx.x;
  float mx = -1e30f;
#pragma unroll
  for (int i = 0; i < 16; ++i) mx = fmaxf(mx, pmax[i * 256 + tid]);
#pragma unroll
  for (int m = 1; m < 64; m <<= 1) mx = fmaxf(mx, __shfl_xor(mx, m));
  __shared__ float sred[4];
  if ((tid & 63) == 0) sred[tid >> 6] = mx;
  __syncthreads();
  if (tid == 0)
    stab[0] = fmaxf(fmaxf(sred[0], sred[1]), fmaxf(sred[2], sred[3]));
}

// ============================================================
// key pass 2: kp -> ksum[m] (atomic), ctxT[j,m] += sum_n v[n,j]*kp[n,m] (atomic)
// ============================================================
__global__ __launch_bounds__(256, 1) void kctx_kernel(
    const u16* __restrict__ qkvb, const u16* __restrict__ projb,
    const float* __restrict__ stab_p,
    float* __restrict__ ctxT, float* __restrict__ ksum)
{
  __shared__ __align__(16) u16 sX[64 * 72];
  __shared__ __align__(16) u16 sVT[64 * 72];
  __shared__ __align__(16) u16 sKpT[256 * 72];
  __shared__ float sDiag[64];
  const int tid = threadIdx.x, lane = tid & 63, wv = tid >> 6;
  const int bh = blockIdx.x, b = bh >> 4, h = bh & 15;
  const int sl = blockIdx.y;
  const float stab = stab_p[0];

  f32x4 cacc[16] = {};
  float ksacc[16] = {};
  const int row_base = wv * 16 + ((lane >> 4) << 2);

  for (int t = 0; t < 8; ++t) {
    const int n0 = sl * 512 + t * 64;
    if (t) __syncthreads();
    for (int i = tid; i < 512; i += 256) {
      int r = i >> 3, c8 = (i & 7) << 3;
      size_t g = ((size_t)(b * NN + n0 + r)) * QKVS + h * DH + c8;
      uint4 xv = *(const uint4*)(qkvb + g + 1024);   // k
      *(uint4*)&sX[r * 72 + c8] = xv;
      uint4 vv = *(const uint4*)(qkvb + g + 2048);   // v
      const u16* pv = (const u16*)&vv;
#pragma unroll
      for (int j = 0; j < 8; ++j) sVT[(c8 + j) * 72 + r] = pv[j];
    }
    __syncthreads();
    {  // diag = 0.5*dn^2*sum x^2 per row
      int r = tid >> 2, qq = tid & 3;
      float s = 0;
#pragma unroll
      for (int j = 0; j < 16; ++j) { float x = bf2f(sX[r * 72 + qq * 16 + j]); s += x * x; }
      s += __shfl_xor(s, 1); s += __shfl_xor(s, 2);
      if (qq == 0) sDiag[r] = DIAGC * s;
    }
    f32x4 dacc[16] = {};
#pragma unroll
    for (int kk = 0; kk < 2; ++kk) {
      const int ko = kk * 32 + ((lane >> 4) << 3);
      bf16x8 a = *(const bf16x8*)&sX[(wv * 16 + (lane & 15)) * 72 + ko];
#pragma unroll
      for (int f = 0; f < 16; ++f) {
        bf16x8 bb = *(const bf16x8*)(projb + (f * 16 + (lane & 15)) * 64 + ko);
        dacc[f] = __builtin_amdgcn_mfma_f32_16x16x32_bf16(a, bb, dacc[f], 0, 0, 0);
      }
    }
    __syncthreads();   // sDiag ready
#pragma unroll
    for (int f = 0; f < 16; ++f) {
      float kvv[4]; float cs = 0;
#pragma unroll
      for (int r = 0; r < 4; ++r) {
        float val = RATIO * (__expf(dacc[f][r] - sDiag[row_base + r] - stab) + KEPSC);
        kvv[r] = val; cs += val;
      }
      cs += __shfl_xor(cs, 16); cs += __shfl_xor(cs, 32);
      ksacc[f] += cs;
      ushort4 pk; pk.x = f2bf(kvv[0]); pk.y = f2bf(kvv[1]); pk.z = f2bf(kvv[2]); pk.w = f2bf(kvv[3]);
      *(ushort4*)&sKpT[(f * 16 + (lane & 15)) * 72 + row_base] = pk;
    }
    __syncthreads();
#pragma unroll
    for (int kk = 0; kk < 2; ++kk) {
      const int ko = kk * 32 + ((lane >> 4) << 3);
      bf16x8 a = *(const bf16x8*)&sVT[(wv * 16 + (lane & 15)) * 72 + ko];
#pragma unroll
      for (int f = 0; f < 16; ++f) {
        bf16x8 bb = *(const bf16x8*)&sKpT[(f * 16 + (lane & 15)) * 72 + ko];
        cacc[f] = __builtin_amdgcn_mfma_f32_16x16x32_bf16(a, bb, cacc[f], 0, 0, 0);
      }
    }
  }
#pragma unroll
  for (int f = 0; f < 16; ++f) {
    const int m = f * 16 + (lane & 15);
#pragma unroll
    for (int r = 0; r < 4; ++r)
      atomicAdd(&ctxT[((size_t)bh * 64 + row_base + r) * 256 + m], cacc[f][r]);
  }
  if (lane < 16) {
#pragma unroll
    for (int f = 0; f < 16; ++f) atomicAdd(&ksum[bh * 256 + f * 16 + lane], ksacc[f]);
  }
}

// ============================================================
// finalize: ctxT f32 -> ctxb bf16
// ============================================================
__global__ __launch_bounds__(256) void ctxfin_kernel(
    const float* __restrict__ ctxT, u16* __restrict__ ctxb)
{
  const int i = blockIdx.x * 256 + threadIdx.x;   // 1048576 f4 slots
  float4 v = ((const float4*)ctxT)[i];
  ushort4 o; o.x = f2bf(v.x); o.y = f2bf(v.y); o.z = f2bf(v.z); o.w = f2bf(v.w);
  ((ushort4*)ctxb)[i] = o;
}

// ============================================================
// query pass: qp features + d_inv + attn = (qp @ ctx) * d_inv
// writes attn IN-PLACE into the q-slice of qkvb (block reads exactly the
// (rows x head-cols) slice it overwrites -> race-free)
// ============================================================
__global__ __launch_bounds__(256, 2) void qattn_kernel(
    u16* qkvb, const u16* __restrict__ projb,
    const u16* __restrict__ ctxb, const float* __restrict__ ksum)
{
  __shared__ __align__(16) u16 sCtx[64 * 256];   // 32KB, swizzled content
  __shared__ __align__(16) u16 sX[64 * 72];
  __shared__ __align__(16) u16 sQp[64 * 264];
  __shared__ float sKsum[256];
  __shared__ float sDiag[64];
  __shared__ float sDinv[64];
  const int tid = threadIdx.x, lane = tid & 63, wv = tid >> 6;
  const int bh = blockIdx.x, b = bh >> 4, h = bh & 15;

  {  // stage ctx (32 KB): LDS linear, global source inverse-swizzled per-lane
    const char* cbase = (const char*)(ctxb + (size_t)bh * 16384);
#pragma unroll
    for (int it = 0; it < 8; ++it) {
      int p = (it * 256 + tid) * 16;
      int ldsb = (it * 256 + (tid & ~63)) * 16;
      int q = p ^ (((p >> 9) & 7) << 4);
      gload_lds16(cbase + q, (char*)sCtx + ldsb);
    }
  }
  sKsum[tid] = ksum[bh * 256 + tid];

  const int row_base = wv * 16 + ((lane >> 4) << 2);
  const int wr = wv >> 1, wc = wv & 1;

  for (int rt = 0; rt < 2; ++rt) {
    const int n0 = (blockIdx.y * 2 + rt) * 64;
    for (int i = tid; i < 512; i += 256) {
      int r = i >> 3, c8 = (i & 7) << 3;
      uint4 v = *(const uint4*)(qkvb + ((size_t)(b * NN + n0 + r)) * QKVS + h * DH + c8);
      *(uint4*)&sX[r * 72 + c8] = v;
    }
    __syncthreads();
    {
      int r = tid >> 2, qq = tid & 3;
      float s = 0;
#pragma unroll
      for (int j = 0; j < 16; ++j) { float x = bf2f(sX[r * 72 + qq * 16 + j]); s += x * x; }
      s += __shfl_xor(s, 1); s += __shfl_xor(s, 2);
      if (qq == 0) sDiag[r] = DIAGC * s;
    }
    f32x4 dacc[16] = {};
#pragma unroll
    for (int kk = 0; kk < 2; ++kk) {
      const int ko = kk * 32 + ((lane >> 4) << 3);
      bf16x8 a = *(const bf16x8*)&sX[(wv * 16 + (lane & 15)) * 72 + ko];
#pragma unroll
      for (int f = 0; f < 16; ++f) {
        bf16x8 bb = *(const bf16x8*)(projb + (f * 16 + (lane & 15)) * 64 + ko);
        dacc[f] = __builtin_amdgcn_mfma_f32_16x16x32_bf16(a, bb, dacc[f], 0, 0, 0);
      }
    }
    __syncthreads();   // sDiag ready
#pragma unroll
    for (int r = 0; r < 4; ++r) {
      const int row = row_base + r;
      float mx = dacc[0][r];
#pragma unroll
      for (int f = 1; f < 16; ++f) mx = fmaxf(mx, dacc[f][r]);
      mx = fmaxf(mx, __shfl_xor(mx, 1));
      mx = fmaxf(mx, __shfl_xor(mx, 2));
      mx = fmaxf(mx, __shfl_xor(mx, 4));
      mx = fmaxf(mx, __shfl_xor(mx, 8));
      const float dg = sDiag[row];
      float ds = 0;
#pragma unroll
      for (int f = 0; f < 16; ++f) {
        float qv = RATIO * (__expf(dacc[f][r] - dg - mx) + KEPSC);
        dacc[f][r] = qv;
        ds += qv * sKsum[f * 16 + (lane & 15)];
      }
      ds += __shfl_xor(ds, 1); ds += __shfl_xor(ds, 2);
      ds += __shfl_xor(ds, 4); ds += __shfl_xor(ds, 8);
      if ((lane & 15) == 0) sDinv[row] = 1.0f / ds;
    }
#pragma unroll
    for (int f = 0; f < 16; ++f)
#pragma unroll
      for (int r = 0; r < 4; ++r)
        sQp[(row_base + r) * 264 + f * 16 + (lane & 15)] = f2bf(dacc[f][r]);
    __syncthreads();

    f32x4 acc2[2][2] = {};
#pragma unroll
    for (int kk = 0; kk < 8; ++kk) {
      const int koe = kk * 32 + ((lane >> 4) << 3);          // element offset
      const int kob = koe * 2;                                // byte offset
      bf16x8 a0 = *(const bf16x8*)&sQp[(wr * 32 + (lane & 15)) * 264 + koe];
      bf16x8 a1 = *(const bf16x8*)&sQp[(wr * 32 + 16 + (lane & 15)) * 264 + koe];
      const int j0 = wc * 32 + (lane & 15), j1 = j0 + 16;
      bf16x8 b0 = *(const bf16x8*)((const char*)sCtx + (((j0 << 9) + kob) ^ ((j0 & 7) << 4)));
      bf16x8 b1 = *(const bf16x8*)((const char*)sCtx + (((j1 << 9) + kob) ^ ((j1 & 7) << 4)));
      acc2[0][0] = __builtin_amdgcn_mfma_f32_16x16x32_bf16(a0, b0, acc2[0][0], 0, 0, 0);
      acc2[0][1] = __builtin_amdgcn_mfma_f32_16x16x32_bf16(a0, b1, acc2[0][1], 0, 0, 0);
      acc2[1][0] = __builtin_amdgcn_mfma_f32_16x16x32_bf16(a1, b0, acc2[1][0], 0, 0, 0);
      acc2[1][1] = __builtin_amdgcn_mfma_f32_16x16x32_bf16(a1, b1, acc2[1][1], 0, 0, 0);
    }
#pragma unroll
    for (int mi = 0; mi < 2; ++mi)
#pragma unroll
      for (int ni = 0; ni < 2; ++ni)
#pragma unroll
        for (int r = 0; r < 4; ++r) {
          const int row = wr * 32 + mi * 16 + ((lane >> 4) << 2) + r;
          const int col = wc * 32 + ni * 16 + (lane & 15);
          float v = acc2[mi][ni][r] * sDinv[row];
          qkvb[((size_t)(b * NN + n0 + row)) * QKVS + h * DH + col] = f2bf(v);
        }
    __syncthreads();   // protect sQp/sDinv before next rt overwrite
  }
}

// ============================================================
// LayerNorms
// ============================================================
__global__ __launch_bounds__(256) void ln1_kernel(
    const float* __restrict__ src, const u16* __restrict__ wout,
    const float* __restrict__ g, const float* __restrict__ be, u16* __restrict__ xb)
{
  const int row = blockIdx.x, tid = threadIdx.x;
  const float4 sv = ((const float4*)(src + (size_t)row * DD))[tid];
  const ushort4 wv = ((const ushort4*)(wout + (size_t)row * DD))[tid];
  float x0 = sv.x + bf2f(wv.x);
  float x1 = sv.y + bf2f(wv.y);
  float x2 = sv.z + bf2f(wv.z);
  float x3 = sv.w + bf2f(wv.w);
  float s = x0 + x1 + x2 + x3;
  float ss = x0 * x0 + x1 * x1 + x2 * x2 + x3 * x3;
#pragma unroll
  for (int m = 1; m < 64; m <<= 1) { s += __shfl_xor(s, m); ss += __shfl_xor(ss, m); }
  __shared__ float red[8];
  if ((tid & 63) == 0) { red[tid >> 6] = s; red[4 + (tid >> 6)] = ss; }
  __syncthreads();
  s = red[0] + red[1] + red[2] + red[3];
  ss = red[4] + red[5] + red[6] + red[7];
  const float mu = s * (1.0f / DD);
  const float rs = rsqrtf(ss * (1.0f / DD) - mu * mu + 1e-5f);
  const float4 gv = ((const float4*)g)[tid];
  const float4 bv = ((const float4*)be)[tid];
  ushort4 o;
  o.x = f2bf((x0 - mu) * rs * gv.x + bv.x);
  o.y = f2bf((x1 - mu) * rs * gv.y + bv.y);
  o.z = f2bf((x2 - mu) * rs * gv.z + bv.z);
  o.w = f2bf((x3 - mu) * rs * gv.w + bv.w);
  ((ushort4*)(xb + (size_t)row * DD))[tid] = o;
}

__global__ __launch_bounds__(256) void ln2_kernel(
    const u16* __restrict__ xb, const u16* __restrict__ ff,
    const float* __restrict__ g, const float* __restrict__ be, float* __restrict__ out)
{
  const int row = blockIdx.x, tid = threadIdx.x;
  const ushort4 xv = ((const ushort4*)(xb + (size_t)row * DD))[tid];
  const ushort4 fv = ((const ushort4*)(ff + (size_t)row * DD))[tid];
  float x0 = bf2f(xv.x) + bf2f(fv.x);
  float x1 = bf2f(xv.y) + bf2f(fv.y);
  float x2 = bf2f(xv.z) + bf2f(fv.z);
  float x3 = bf2f(xv.w) + bf2f(fv.w);
  float s = x0 + x1 + x2 + x3;
  float ss = x0 * x0 + x1 * x1 + x2 * x2 + x3 * x3;
#pragma unroll
  for (int m = 1; m < 64; m <<= 1) { s += __shfl_xor(s, m); ss += __shfl_xor(ss, m); }
  __shared__ float red[8];
  if ((tid & 63) == 0) { red[tid >> 6] = s; red[4 + (tid >> 6)] = ss; }
  __syncthreads();
  s = red[0] + red[1] + red[2] + red[3];
  ss = red[4] + red[5] + red[6] + red[7];
  const float mu = s * (1.0f / DD);
  const float rs = rsqrtf(ss * (1.0f / DD) - mu * mu + 1e-5f);
  const float4 gv = ((const float4*)g)[tid];
  const float4 bv = ((const float4*)be)[tid];
  float4 o;
  o.x = (x0 - mu) * rs * gv.x + bv.x;
  o.y = (x1 - mu) * rs * gv.y + bv.y;
  o.z = (x2 - mu) * rs * gv.z + bv.z;
  o.w = (x3 - mu) * rs * gv.w + bv.w;
  ((float4*)(out + (size_t)row * DD))[tid] = o;
}

// ============================================================
// launch
// ============================================================
extern "C" void kernel_launch(void* const* d_in, const int* in_sizes, int n_in,
                              void* d_out, int out_size, void* d_ws, size_t ws_size,
                              hipStream_t stream) {
  (void)in_sizes; (void)n_in; (void)out_size; (void)ws_size;
  const float* src   = (const float*)d_in[0];
  const float* Wq    = (const float*)d_in[1];
  const float* Wk    = (const float*)d_in[2];
  const float* Wv    = (const float*)d_in[3];
  const float* Wout  = (const float*)d_in[4];
  const float* b_out = (const float*)d_in[5];
  const float* proj  = (const float*)d_in[6];
  const float* g1    = (const float*)d_in[7];
  const float* be1   = (const float*)d_in[8];
  const float* W1    = (const float*)d_in[9];
  const float* b1    = (const float*)d_in[10];
  const float* W2    = (const float*)d_in[11];
  const float* b2    = (const float*)d_in[12];
  const float* g2    = (const float*)d_in[13];
  const float* be2   = (const float*)d_in[14];

  char* ws = (char*)d_ws;
  // layout (bytes):
  //  S0 [0, 33.55M): srcb (cast->QKVgemm) -> ctxb@0 (2MB, ctxfin->qattn) -> h1 head
  //  [33.55M, 134.2M): qkvb [16384][3072]; attn written in-place into q-slice;
  //                    xb at middle third after qattn; woutb->ff at last third
  //  [134.2M, 151.03M): weights wqkvb|wob|w1b|w2b|projb
  //  [151.03M, 155.3M): ctxT(4M) ksum(64K) pmax(16K) stab
  constexpr size_t OFF_SRCB = 0;
  constexpr size_t OFF_QKV  = 33554432;
  constexpr size_t OFF_XB   = 67108864;
  constexpr size_t OFF_WOUTB= 100663296;
  constexpr size_t OFF_WQKV = 134217728;
  constexpr size_t OFF_WO   = 140509184;
  constexpr size_t OFF_W1   = 142606336;
  constexpr size_t OFF_W2   = 146800640;
  constexpr size_t OFF_PROJ = 150994944;
  constexpr size_t OFF_CTXT = 151027712;
  constexpr size_t OFF_KSUM = 155222016;
  constexpr size_t OFF_PMAX = 155287552;
  constexpr size_t OFF_STAB = 155303936;

  u16* srcb  = (u16*)(ws + OFF_SRCB);
  u16* qkvb  = (u16*)(ws + OFF_QKV);
  u16* wqkvb = (u16*)(ws + OFF_WQKV);      // [3072][1024] (Wq|Wk|Wv rows)
  u16* wob   = (u16*)(ws + OFF_WO);
  u16* w1b   = (u16*)(ws + OFF_W1);
  u16* w2b   = (u16*)(ws + OFF_W2);
  u16* projb = (u16*)(ws + OFF_PROJ);
  float* ctxT = (float*)(ws + OFF_CTXT);
  float* ksum = (float*)(ws + OFF_KSUM);
  float* pmax = (float*)(ws + OFF_PMAX);
  float* stab = (float*)(ws + OFF_STAB);
  u16* ctxb  = (u16*)(ws + OFF_SRCB);      // 2MB, alias srcb (dead after QKV gemm)
  u16* woutb = (u16*)(ws + OFF_WOUTB);     // last third of qkvb (dead after Wout gemm A-read)
  u16* xb    = (u16*)(ws + OFF_XB);        // middle third (dead after Wout gemm)
  u16* h1    = (u16*)(ws + OFF_SRCB);      // [0, 67.1M)
  u16* ff    = (u16*)(ws + OFF_WOUTB);     // woutb slot (dead after ln1)

  // casts + ctxT/ksum zero-init
  cast_kernel<<<4096, 256, 0, stream>>>(src, srcb, RT * DD / 4);
  cast_weights_kernel<<<2048, 256, 0, stream>>>(Wq, Wk, Wv, Wout, W1, W2, proj,
                                                wqkvb, wob, w1b, w2b, projb);
  hipMemsetAsync(ws + OFF_CTXT, 0, 4194304 + 65536, stream);

  // fused QKV projection: [16384][3072]
  gemm_bt<0><<<dim3(QKVS / 128, RT / 256), 512, 0, stream>>>(srcb, DD, wqkvb, qkvb, nullptr, QKVS, DD);

  // performer features
  kmax_kernel<<<dim3(64, 64), 256, 0, stream>>>(qkvb, projb, pmax);
  reduce_max_kernel<<<1, 256, 0, stream>>>(pmax, stab);
  kctx_kernel<<<dim3(64, 8), 256, 0, stream>>>(qkvb, projb, stab, ctxT, ksum);
  ctxfin_kernel<<<4096, 256, 0, stream>>>(ctxT, ctxb);
  qattn_kernel<<<dim3(64, 32), 256, 0, stream>>>(qkvb, projb, ctxb, ksum);

  // Wout (+bias) -> bf16 (A = attn, in-place in qkvb q-slice, lda=3072)
  gemm_bt<3><<<dim3(DD / 128, RT / 256), 512, 0, stream>>>(qkvb, QKVS, wob, woutb, b_out, DD, DD);
  ln1_kernel<<<RT, 256, 0, stream>>>(src, woutb, g1, be1, xb);

  // FFN
  gemm_bt<2><<<dim3(2048 / 128, RT / 256), 512, 0, stream>>>(xb, DD, w1b, h1, b1, 2048, DD);
  gemm_bt<3><<<dim3(DD / 128, RT / 256), 512, 0, stream>>>(h1, 2048, w2b, ff, b2, DD, 2048);
  ln2_kernel<<<RT, 256, 0, stream>>>(xb, ff, g2, be2, (float*)d_out);
}